// Round 15
// baseline (352.270 us; speedup 1.0000x reference)
//
#include <hip/hip_runtime.h>
#include <math.h>

#define BB 2
#define TT 2048
#define DD 1024
#define RS 16
#define MT (BB*TT)      // 4096 flattened rows
#define GLD 640         // stage-1 concat output width (611 used, padded)
#define KAUG 1056       // 1024 + 16 (zB/A1) + 16 zero pad; multiple of 32

typedef __attribute__((ext_vector_type(8))) short s16x8;
typedef __attribute__((ext_vector_type(4))) float f32x4;

__device__ __forceinline__ short f2bf(float f) {
    union { float f; unsigned u; } v; v.f = f;
    unsigned r = (v.u + 0x7fffu + ((v.u >> 16) & 1u)) >> 16;
    return (short)r;
}
__device__ __forceinline__ float bf2f(short s) {
    union { unsigned u; float f; } v; v.u = ((unsigned)(unsigned short)s) << 16;
    return v.f;
}

__device__ __forceinline__ void gload16(const void* g, void* l) {
    __builtin_amdgcn_global_load_lds((const __attribute__((address_space(1))) void*)g,
                                     (__attribute__((address_space(3))) void*)l, 16, 0, 0);
}

// XCD-aware block swizzle (all grids are multiples of 8 -> bijective).
__device__ __forceinline__ void xcd_swz(int& bx, int& by, int& bz)
{
    const int gx = gridDim.x, gy = gridDim.y;
    const int n = gx * gy * (int)gridDim.z;
    int flat = (bz * gy + by) * gx + bx;
    const int cpx = n >> 3;
    flat = (flat & 7) * cpx + (flat >> 3);
    bx = flat % gx; by = (flat / gx) % gy; bz = flat / (gx * gy);
}

// ---------------------------------------------------------------------------
// 8-wave (512-thr) pipelined 128x128 NT core, 2M x 4N wave layout.
// r13-proven for single-pass GEMMs (ctx/Wo/s1/stage2): 16 waves/CU at
// 2 blocks/CU hides the stage/barrier latency (m114). acc[4][2] = 32 VGPR.
// Counted vmcnt 2 (depth2) / 4 (depth3); raw s_barrier; granule XOR-swizzle.
// ---------------------------------------------------------------------------
template<int DEPTH>
__device__ __forceinline__ void gemm_core128p(const short* __restrict__ A,
                                              const short* __restrict__ Bt,
                                              int K, int lda, int ldb,
                                              int bi, int bj, short* smem,
                                              f32x4 (&acc)[4][2])
{
    const int tid = threadIdx.x;
    const int wv = tid >> 6, lane = tid & 63;
    const int wr = (wv >> 2) * 64, wc = (wv & 3) * 32;

#pragma unroll
    for (int m = 0; m < 4; ++m)
#pragma unroll
        for (int n = 0; n < 2; ++n) acc[m][n] = (f32x4){0.f, 0.f, 0.f, 0.f};

    const int srow = wv * 16 + (lane >> 2);                // staging row 0..127
    const int sg   = ((lane & 3) ^ ((srow >> 1) & 3)) * 8; // swizzled src granule
    const int frow = lane & 15;
    const int gidx = lane >> 4;
    const int koff = (gidx ^ ((frow >> 1) & 3)) * 8;       // swizzled read offset

    const int nt = K >> 5;
    const long arow = (long)(bi + srow) * lda + sg;
    const long brow = (long)(bj + srow) * ldb + sg;

    auto stage = [&](int t, int q) {
        short* As = smem + q * 8192;
        short* Bs = As + 4096;
        const int k0 = t << 5;
        gload16(A + arow + k0, As + wv*512);
        gload16(Bt + brow + k0, Bs + wv*512);
    };

    stage(0, 0);
    if (nt > 1) stage(1, 1);
    if (DEPTH == 3) { if (nt > 2) stage(2, 2); }

    int q = 0;
    for (int t = 0; t < nt; ++t) {
        const int rem = nt - 1 - t;
        if (DEPTH == 3 && rem >= 2) asm volatile("s_waitcnt vmcnt(4)" ::: "memory");
        else if (rem >= 1)          asm volatile("s_waitcnt vmcnt(2)" ::: "memory");
        else                        asm volatile("s_waitcnt vmcnt(0)" ::: "memory");
        __builtin_amdgcn_s_barrier();          // all waves' tile-t data visible

        const short* As = smem + q * 8192;
        const short* Bs = As + 4096;
        s16x8 af[4], bfr[2];
#pragma unroll
        for (int m = 0; m < 4; ++m)
            af[m] = *(const s16x8*)&As[(wr + m*16 + frow) * 32 + koff];
#pragma unroll
        for (int n = 0; n < 2; ++n)
            bfr[n] = *(const s16x8*)&Bs[(wc + n*16 + frow) * 32 + koff];
        asm volatile("s_waitcnt lgkmcnt(0)" ::: "memory");  // reads in registers
        __builtin_amdgcn_sched_barrier(0);                  // rule-18 fence
        __builtin_amdgcn_s_barrier();          // all waves done READING buf q

        if (t + DEPTH < nt) stage(t + DEPTH, q);  // overwrite safe; overlaps MFMA

#pragma unroll
        for (int m = 0; m < 4; ++m)
#pragma unroll
            for (int n = 0; n < 2; ++n)
                acc[m][n] = __builtin_amdgcn_mfma_f32_16x16x32_bf16(af[m], bfr[n], acc[m][n], 0, 0, 0);
        q = (q == DEPTH - 1) ? 0 : q + 1;
    }
}

// ---------------------------------------------------------------------------
// 4-wave (256-thr) depth-2 core, 2x2 wave layout, acc[4][4]. r11-proven for
// hmhs (59.5us, FETCH 43.7MB); r13's 8-wave variant regressed hmhs to 65us
// (FETCH 55.7MB from L2 thrash with two 512-thr blocks). Used by hmhs ONLY.
// ---------------------------------------------------------------------------
__device__ __forceinline__ void gemm_core128p4(const short* __restrict__ A,
                                               const short* __restrict__ Bt,
                                               int K, int lda, int ldb,
                                               int bi, int bj, short* smem,
                                               f32x4 (&acc)[4][4])
{
    const int tid = threadIdx.x;
    const int wv = tid >> 6, lane = tid & 63;
    const int wr = (wv >> 1) * 64, wc = (wv & 1) * 64;

#pragma unroll
    for (int m = 0; m < 4; ++m)
#pragma unroll
        for (int n = 0; n < 4; ++n) acc[m][n] = (f32x4){0.f, 0.f, 0.f, 0.f};

    const int srow = wv * 16 + (lane >> 2);
    const int sg   = ((lane & 3) ^ ((srow >> 1) & 3)) * 8;
    const int frow = lane & 15;
    const int gidx = lane >> 4;
    const int koff = (gidx ^ ((frow >> 1) & 3)) * 8;

    const int nt = K >> 5;
    const long arow = (long)(bi + srow) * lda + sg;
    const long brow = (long)(bj + srow) * ldb + sg;

    auto stage = [&](int t, int q) {
        short* As = smem + q * 8192;
        short* Bs = As + 4096;
        const int k0 = t << 5;
#pragma unroll
        for (int p = 0; p < 2; ++p) {
            gload16(A + arow + (long)p * 64 * lda + k0, As + p*2048 + wv*512);
            gload16(Bt + brow + (long)p * 64 * ldb + k0, Bs + p*2048 + wv*512);
        }
    };

    stage(0, 0);
    if (nt > 1) stage(1, 1);

    int q = 0;
    for (int t = 0; t < nt; ++t) {
        const int rem = nt - 1 - t;
        if (rem >= 1) asm volatile("s_waitcnt vmcnt(4)" ::: "memory");
        else          asm volatile("s_waitcnt vmcnt(0)" ::: "memory");
        __builtin_amdgcn_s_barrier();

        const short* As = smem + q * 8192;
        const short* Bs = As + 4096;
        s16x8 af[4], bfr[4];
#pragma unroll
        for (int m = 0; m < 4; ++m)
            af[m] = *(const s16x8*)&As[(wr + m*16 + frow) * 32 + koff];
#pragma unroll
        for (int n = 0; n < 4; ++n)
            bfr[n] = *(const s16x8*)&Bs[(wc + n*16 + frow) * 32 + koff];
        asm volatile("s_waitcnt lgkmcnt(0)" ::: "memory");
        __builtin_amdgcn_sched_barrier(0);
        __builtin_amdgcn_s_barrier();

        if (t + 2 < nt) stage(t + 2, q);

#pragma unroll
        for (int m = 0; m < 4; ++m)
#pragma unroll
            for (int n = 0; n < 4; ++n)
                acc[m][n] = __builtin_amdgcn_mfma_f32_16x16x32_bf16(af[m], bfr[n], acc[m][n], 0, 0, 0);
        q ^= 1;
    }
}

// Generic batched NT GEMM; STORE 0 = fp32 out, 1 = bf16 out.
template<int STORE>
__global__ __launch_bounds__(512)
void gemm_nt(const short* __restrict__ A, const short* __restrict__ Bt,
             void* __restrict__ Cv, int K, int lda, int ldb, int ldc,
             long sA, long sB, long sC)
{
    int bx = blockIdx.x, by = blockIdx.y, bz = blockIdx.z;
    xcd_swz(bx, by, bz);
    const short* Ab = A  + (long)bz * sA;
    const short* Bb = Bt + (long)bz * sB;
    const int bi = by * 128, bj = bx * 128;
    __shared__ __align__(16) short smem[16384];
    f32x4 acc[4][2];
    gemm_core128p<2>(Ab, Bb, K, lda, ldb, bi, bj, smem, acc);

    const int lane = threadIdx.x & 63, wv = threadIdx.x >> 6;
    const int wr = (wv >> 2) * 64, wc = (wv & 3) * 32;
    const int col0 = lane & 15, row0 = (lane >> 4) * 4;
#pragma unroll
    for (int m = 0; m < 4; ++m)
#pragma unroll
        for (int n = 0; n < 2; ++n)
#pragma unroll
            for (int r = 0; r < 4; ++r) {
                int i = bi + wr + m*16 + row0 + r;
                int j = bj + wc + n*16 + col0;
                if (STORE == 0)
                    ((float*)Cv + (long)bz * sC)[(long)i * ldc + j] = acc[m][n][r];
                else
                    ((short*)Cv + (long)bz * sC)[(long)i * ldc + j] = f2bf(acc[m][n][r]);
            }
}

// ---------------------------------------------------------------------------
// Stage-1: xb @ WcatT^T. Epilogue: cols <512 -> Gb512 bf16 (stage-2 input);
// cols 512..610 scattered directly to SoA generator arrays (G never stored).
// Also zeroes aug pad cols 1040..1055 (at j==512, once per row).
// ---------------------------------------------------------------------------
__global__ __launch_bounds__(512)
void gemm_s1(const short* __restrict__ xb, const short* __restrict__ WcatT,
             short* __restrict__ Gb512,
             float* __restrict__ d1, float* __restrict__ d1s, float* __restrict__ d2,
             float* __restrict__ B1T, float* __restrict__ B1sT, float* __restrict__ A2T,
             short* __restrict__ B2T,
             short* __restrict__ QGaug, short* __restrict__ QSGaug,
             short* __restrict__ KBaug, short* __restrict__ KSBaug)
{
    int bx = blockIdx.x, by = blockIdx.y, bz = blockIdx.z;
    xcd_swz(bx, by, bz);
    const int bi = by * 128, bj = bx * 128;
    __shared__ __align__(16) short smem[16384];
    f32x4 acc[4][2];
    gemm_core128p<2>(xb, WcatT, DD, DD, DD, bi, bj, smem, acc);

    const int lane = threadIdx.x & 63, wv = threadIdx.x >> 6;
    const int wr = (wv >> 2) * 64, wc = (wv & 3) * 32;
    const int col0 = lane & 15, row0 = (lane >> 4) * 4;
#pragma unroll
    for (int m = 0; m < 4; ++m)
#pragma unroll
        for (int n = 0; n < 2; ++n)
#pragma unroll
            for (int r = 0; r < 4; ++r) {
                int i = bi + wr + m*16 + row0 + r;
                int j = bj + wc + n*16 + col0;
                float val = acc[m][n][r];
                if (j < 512) {
                    Gb512[(long)i * 512 + j] = f2bf(val);
                } else if (j == 512) {
                    d1[i] = val;
                    for (int q = 0; q < RS; ++q) {
                        QGaug [(long)i * KAUG + 1040 + q] = 0;
                        QSGaug[(long)i * KAUG + 1040 + q] = 0;
                        KBaug [(long)i * KAUG + 1040 + q] = 0;
                        KSBaug[(long)i * KAUG + 1040 + q] = 0;
                    }
                } else if (j < 529) {
                    KBaug[(long)i * KAUG + 1024 + (j - 513)] = f2bf(val);
                } else if (j < 545) {
                    B1T[(long)(j - 529) * MT + i] = val;
                } else if (j == 545) {
                    d1s[i] = val;
                } else if (j < 562) {
                    KSBaug[(long)i * KAUG + 1024 + (j - 546)] = f2bf(val);
                } else if (j < 578) {
                    B1sT[(long)(j - 562) * MT + i] = val;
                } else if (j == 578) {
                    d2[i] = val;
                } else if (j < 595) {
                    A2T[(long)(j - 579) * MT + i] = val;
                } else if (j < 611) {
                    B2T[(long)(j - 595) * MT + i] = f2bf(val);
                }
            }
}

// ---------------------------------------------------------------------------
// E[kind][b][c][r] = sum_t Gb512[b*TT+t][col0(kind)+c] * BT_kind[r][b*TT+t]
// ---------------------------------------------------------------------------
__global__ __launch_bounds__(256)
void e_kernel(const short* __restrict__ Gb512, const float* __restrict__ BT0,
              float* __restrict__ E)
{
    const int tc = blockIdx.x, b = blockIdx.y, kind = blockIdx.z;
    const int col0 = (kind == 0) ? 128 : (kind == 1) ? 320 : 384;
    const float* BT = BT0 + (size_t)kind * RS * MT;
    const int c = threadIdx.x & 63, rg = threadIdx.x >> 6;
    float acc[4] = {0.f, 0.f, 0.f, 0.f};
    const int t0 = tc * (TT / 16);
#pragma unroll 2
    for (int tt = 0; tt < TT / 16; ++tt) {
        const long gi = (long)b * TT + t0 + tt;
        float g = bf2f(Gb512[gi * 512 + col0 + c]);
#pragma unroll
        for (int q = 0; q < 4; ++q)
            acc[q] = fmaf(g, BT[(long)(rg * 4 + q) * MT + gi], acc[q]);
    }
#pragma unroll
    for (int q = 0; q < 4; ++q)
        atomicAdd(&E[(((long)kind * BB + b) * 64 + c) * RS + rg * 4 + q], acc[q]);
}

// ---------------------------------------------------------------------------
// c1w: C1[kind][b][d][r] = sum_c W2T[s(kind)][d][c] * E[kind][b][c][r]
// kind 2 writes A2tV[b][r][d] layout instead.
// ---------------------------------------------------------------------------
__global__ __launch_bounds__(256)
void c1w_kernel(const short* __restrict__ W2, const float* __restrict__ E,
                float* __restrict__ C1, float* __restrict__ A2tV)
{
    const int d0 = blockIdx.x * 64, kind = blockIdx.y, b = blockIdx.z;
    const int s = (kind == 0) ? 2 : (kind == 1) ? 5 : 6;
    __shared__ float El[64][RS];
    {
        const float* Eb = E + ((long)kind * BB + b) * 64 * RS;
        int q = threadIdx.x;
#pragma unroll
        for (int k = 0; k < 4; ++k) ((float*)El)[q + 256 * k] = Eb[q + 256 * k];
    }
    __syncthreads();
    const int dl = threadIdx.x & 63, rg = threadIdx.x >> 6;
    const int d = d0 + dl;
    const short* wrow = W2 + ((long)s * DD + d) * 64;
    float acc[4] = {0.f, 0.f, 0.f, 0.f};
#pragma unroll
    for (int c8 = 0; c8 < 8; ++c8) {
        s16x8 wv = *(const s16x8*)&wrow[c8 * 8];
#pragma unroll
        for (int u = 0; u < 8; ++u) {
            float w = bf2f(wv[u]);
#pragma unroll
            for (int q = 0; q < 4; ++q)
                acc[q] = fmaf(w, El[c8 * 8 + u][rg * 4 + q], acc[q]);
        }
    }
    if (kind < 2) {
        float* dst = C1 + (size_t)kind * BB * DD * RS;
#pragma unroll
        for (int q = 0; q < 4; ++q)
            dst[((long)b * DD + d) * RS + rg * 4 + q] = acc[q];
    } else {
#pragma unroll
        for (int q = 0; q < 4; ++q)
            A2tV[((long)b * RS + rg * 4 + q) * DD + d] = acc[q];
    }
}

// ---------------------------------------------------------------------------
// hmhs_fused: two sequential 4-wave depth-2 core passes (gate, scale),
// 32 KB LDS, 256 threads (r11-proven config). Epilogue:
//   P = fast_softplus(hs) * relu(hm)  (bf16, norm deferred)
//   rowsum += sum_j hm^2              (shuffle-reduce + atomics)
//   hBraw[i][r16] += sum_j hv_fp32[i][j] * B2T[r16][j]   (finish_kernel
//     fused in; norm iv factored out -- ctx applies iv AFTER rank-16,
//     since iv*(P@VDT) + (iv*hB)@A2tV == iv*(P@VDT + hBraw@A2tV)).
// ---------------------------------------------------------------------------
__global__ __launch_bounds__(256)
void hmhs_kernel(const short* __restrict__ QGaug, const short* __restrict__ QSGaug,
                 const short* __restrict__ KBaug, const short* __restrict__ KSBaug,
                 const short* __restrict__ B2T,
                 short* __restrict__ P, float* __restrict__ rowsum,
                 float* __restrict__ hBraw)
{
    int bx = blockIdx.x, by = blockIdx.y, bz = blockIdx.z;
    xcd_swz(bx, by, bz);
    const int b = bz;
    const int bi = by * 128, bj = bx * 128;
    __shared__ __align__(16) short smem[16384];
    f32x4 acc[4][4], acc2[4][4];
    gemm_core128p4(QGaug  + (long)b * TT * KAUG, KBaug  + (long)b * TT * KAUG,
                   KAUG, KAUG, KAUG, bi, bj, smem, acc);
    gemm_core128p4(QSGaug + (long)b * TT * KAUG, KSBaug + (long)b * TT * KAUG,
                   KAUG, KAUG, KAUG, bi, bj, smem, acc2);

    const int lane = threadIdx.x & 63, wv = threadIdx.x >> 6;
    const int wr = (wv >> 1) * 64, wc = (wv & 1) * 64;
    const int col0 = lane & 15, row0 = (lane >> 4) * 4;
    short* Pb = P + (long)b * TT * TT;
    const long tb = (long)b * TT;

    float ss[4][4];
#pragma unroll
    for (int m = 0; m < 4; ++m)
#pragma unroll
        for (int r = 0; r < 4; ++r) ss[m][r] = 0.f;

#pragma unroll
    for (int m = 0; m < 4; ++m)
#pragma unroll
        for (int n = 0; n < 4; ++n)
#pragma unroll
            for (int r = 0; r < 4; ++r) {
                int i = bi + wr + m*16 + row0 + r;
                int j = bj + wc + n*16 + col0;
                float hmv = acc[m][n][r];
                float sv  = acc2[m][n][r];
                // fast softplus: 2 HW transcendentals (error << bf16 rounding)
                float sp  = fmaxf(sv, 0.f) + __logf(1.f + __expf(-fabsf(sv)));
                float hv  = sp * fmaxf(hmv, 0.f);
                Pb[(long)i * TT + j] = f2bf(hv);
                ss[m][r] = fmaf(hmv, hmv, ss[m][r]);
                acc[m][n][r] = hv;            // stash hv for hB reduction
            }

    // rowsum: reduce over the 16 col0 lanes, one atomic per row
#pragma unroll
    for (int m = 0; m < 4; ++m)
#pragma unroll
        for (int r = 0; r < 4; ++r) {
            float v = ss[m][r];
            v += __shfl_xor(v, 1, 64);
            v += __shfl_xor(v, 2, 64);
            v += __shfl_xor(v, 4, 64);
            v += __shfl_xor(v, 8, 64);
            if (col0 == 0)
                atomicAdd(&rowsum[tb + bi + wr + m*16 + row0 + r], v);
        }

    // hBraw partials: for each r16, dot this block's 128-col slice of hv
    // with B2T[r16][:], reduce over col0 lanes, one atomic per row.
#pragma unroll 4
    for (int r16 = 0; r16 < RS; ++r16) {
        const short* br = B2T + (long)r16 * MT + tb + bj + wc;
        float b2[4];
#pragma unroll
        for (int n = 0; n < 4; ++n) b2[n] = bf2f(br[n*16 + col0]);
#pragma unroll
        for (int m = 0; m < 4; ++m)
#pragma unroll
            for (int r = 0; r < 4; ++r) {
                float v = 0.f;
#pragma unroll
                for (int n = 0; n < 4; ++n) v = fmaf(acc[m][n][r], b2[n], v);
                v += __shfl_xor(v, 1, 64);
                v += __shfl_xor(v, 2, 64);
                v += __shfl_xor(v, 4, 64);
                v += __shfl_xor(v, 8, 64);
                if (col0 == 0)
                    atomicAdd(&hBraw[(tb + bi + wr + m*16 + row0 + r) * RS + r16], v);
            }
    }
}

// ---------------------------------------------------------------------------
// Stage-2 multi-slice GEMM (K=64 per pass).
// mode 0 (GATE):   two passes (sa,sb); out bf16(acc*acc2) at ldc KAUG.
// mode 1 (SCALED): outS bf16(acc*rs[i]) at ldc KAUG.
// mode 3 (BF16):   outS bf16 ldc DD.
// ---------------------------------------------------------------------------
struct S2S { int mode, sa, sb; short* outS; const float* rs; };
struct S2A { S2S sl[6]; };

__global__ __launch_bounds__(512)
void stage2_kernel(const short* __restrict__ Gb, const short* __restrict__ W2,
                   S2A args)
{
    int bx = blockIdx.x, by = blockIdx.y, bz = blockIdx.z;
    xcd_swz(bx, by, bz);
    const S2S sl = args.sl[bz];
    const int bi = by * 128, bj = bx * 128;
    __shared__ __align__(16) short smem[16384];
    f32x4 acc[4][2];
    gemm_core128p<2>(Gb + sl.sa * 64, W2 + (long)sl.sa * DD * 64, 64, 512, 64, bi, bj, smem, acc);
    f32x4 acc2[4][2];
    if (sl.mode == 0)
        gemm_core128p<2>(Gb + sl.sb * 64, W2 + (long)sl.sb * DD * 64, 64, 512, 64, bi, bj, smem, acc2);

    const int lane = threadIdx.x & 63, wv = threadIdx.x >> 6;
    const int wr = (wv >> 2) * 64, wc = (wv & 3) * 32;
    const int col0 = lane & 15, row0 = (lane >> 4) * 4;
#pragma unroll
    for (int m = 0; m < 4; ++m)
#pragma unroll
        for (int n = 0; n < 2; ++n)
#pragma unroll
            for (int r = 0; r < 4; ++r) {
                int i = bi + wr + m*16 + row0 + r;
                int j = bj + wc + n*16 + col0;
                float val = acc[m][n][r];
                if (sl.mode == 0) {
                    sl.outS[(long)i * KAUG + j] = f2bf(val * acc2[m][n][r]);
                } else if (sl.mode == 1) {
                    sl.outS[(long)i * KAUG + j] = f2bf(val * sl.rs[i]);
                } else {
                    sl.outS[(long)i * DD + j] = f2bf(val);
                }
            }
}

// ---------------------------------------------------------------------------
// Context GEMM, fused epilogue:
//   cm = bf16( iv[i] * (P@VDT^T + hBraw@A2tV) * mvo )
// (iv applied AFTER the rank-16 correction; hBraw is un-normalized.)
// DEPTH=3 (longest K-loop, single accumulator). mvo read as bf16.
// ---------------------------------------------------------------------------
__global__ __launch_bounds__(512)
void ctx_kernel(const short* __restrict__ P, const short* __restrict__ VDT,
                const short* __restrict__ mvo, const float* __restrict__ hBraw,
                const float* __restrict__ A2tV, const float* __restrict__ rowsum,
                short* __restrict__ cm)
{
    int bx = blockIdx.x, by = blockIdx.y, bz = blockIdx.z;
    xcd_swz(bx, by, bz);
    const int b = bz;
    const int bi = by * 128, bj = bx * 128;
    __shared__ __align__(16) short smem[24576];
    f32x4 acc[4][2];
    gemm_core128p<3>(P + (long)b * TT * TT, VDT + (long)b * DD * TT, TT, TT, TT, bi, bj, smem, acc);

    const int lane = threadIdx.x & 63, wv = threadIdx.x >> 6;
    const int wr = (wv >> 2) * 64, wc = (wv & 3) * 32;
    const int col0 = lane & 15, row0 = (lane >> 4) * 4;
    const float* a2 = A2tV + (long)b * RS * DD;

    // rank-16 correction with RAW hB
#pragma unroll
    for (int r16 = 0; r16 < RS; ++r16) {
        float a2v[2];
#pragma unroll
        for (int n = 0; n < 2; ++n)
            a2v[n] = a2[(long)r16 * DD + bj + wc + n*16 + col0];
#pragma unroll
        for (int m = 0; m < 4; ++m)
#pragma unroll
            for (int r = 0; r < 4; ++r) {
                long gi = (long)b * TT + bi + wr + m*16 + row0 + r;
                float hb = hBraw[gi * RS + r16];
#pragma unroll
                for (int n = 0; n < 2; ++n)
                    acc[m][n][r] = fmaf(hb, a2v[n], acc[m][n][r]);
            }
    }
    // apply deferred L2-norm inv, then mvo gate, store bf16
#pragma unroll
    for (int m = 0; m < 4; ++m)
#pragma unroll
        for (int r = 0; r < 4; ++r) {
            long gi = (long)b * TT + bi + wr + m*16 + row0 + r;
            float iv = 1.f / (sqrtf(rowsum[gi]) + 1e-8f);
#pragma unroll
            for (int n = 0; n < 2; ++n) {
                int j = bj + wc + n*16 + col0;
                cm[gi * DD + j] = f2bf(acc[m][n][r] * iv * bf2f(mvo[gi * DD + j]));
            }
        }
}

// ---------------------------------------------------------------------------
// Weight prep
// ---------------------------------------------------------------------------
struct ConcatArgs { const float* p[17]; int col0[17]; int wid[17]; };

__global__ __launch_bounds__(256)
void concat_w1_kernel(ConcatArgs a, short* __restrict__ WcatT,
                      float* __restrict__ zp, int zn)
{
    const int q = blockIdx.x * 256 + threadIdx.x;
    if (q < zn) zp[q] = 0.f;
    const int n = blockIdx.x;
    int s = -1, c = 0;
    for (int i = 0; i < 17; ++i)
        if (n >= a.col0[i] && n < a.col0[i] + a.wid[i]) { s = i; c = n - a.col0[i]; }
    for (int k = threadIdx.x; k < DD; k += 256)
        WcatT[(long)n * DD + k] = (s < 0) ? (short)0 : f2bf(a.p[s][(long)k * a.wid[s] + c]);
}

struct Ptrs8 { const float* p[8]; };

__global__ __launch_bounds__(256)
void concat_w2_kernel(Ptrs8 a, short* __restrict__ W2catT)
{
    const int s = blockIdx.y, n0 = blockIdx.x * 64;
    const int tx = threadIdx.x & 63, ty = threadIdx.x >> 6;
    __shared__ float t[64][65];
    const float* W2 = a.p[s];
    for (int kk = ty; kk < 64; kk += 4) t[kk][tx] = W2[(long)kk * DD + n0 + tx];
    __syncthreads();
    for (int n = ty; n < 64; n += 4)
        W2catT[((long)s * DD + n0 + n) * 64 + tx] = f2bf(t[tx][n]);
}

__global__ __launch_bounds__(256)
void f2bf_vec_kernel(const float* __restrict__ in, short* __restrict__ o, long n4)
{
    long i = (long)blockIdx.x * 256 + threadIdx.x;
    if (i < n4) {
        float4 v = ((const float4*)in)[i];
        short4 r; r.x = f2bf(v.x); r.y = f2bf(v.y); r.z = f2bf(v.z); r.w = f2bf(v.w);
        ((short4*)o)[i] = r;
    }
}

// zB[i][:] = qg[i][:1024] @ C1[b] (fp32 C1) -> aug cols 1024..1039
__global__ __launch_bounds__(256)
void zb_kernel(short* __restrict__ aug0, const float* __restrict__ C10)
{
    const int gi = blockIdx.x, path = blockIdx.y, b = gi >> 11, tid = threadIdx.x;
    short* aug = aug0 + (size_t)path * MT * KAUG;
    const float* c1 = C10 + (size_t)path * BB * DD * RS + (long)b * DD * RS;
    const short* qrow = aug + (long)gi * KAUG;
    float acc[RS];
#pragma unroll
    for (int r = 0; r < RS; ++r) acc[r] = 0.f;
#pragma unroll
    for (int c = 0; c < 4; ++c) {
        int d = tid + 256 * c;
        float q = bf2f(qrow[d]);
        const float* cr = c1 + (long)d * RS;
#pragma unroll
        for (int r = 0; r < RS; ++r) acc[r] = fmaf(q, cr[r], acc[r]);
    }
#pragma unroll
    for (int r = 0; r < RS; ++r)
#pragma unroll
        for (int off = 32; off; off >>= 1) acc[r] += __shfl_down(acc[r], off, 64);
    __shared__ float red[4][RS];
    if ((tid & 63) == 0)
#pragma unroll
        for (int r = 0; r < RS; ++r) red[tid >> 6][r] = acc[r];
    __syncthreads();
    if (tid < RS)
        aug[(long)gi * KAUG + 1024 + tid] =
            f2bf(red[0][tid] + red[1][tid] + red[2][tid] + red[3][tid]);
}

// ---------------------------------------------------------------------------
// vdT[b][d][t] = bf16(vb[b][t][d] * d2[b*TT+t])   (vb bf16)
// ---------------------------------------------------------------------------
__global__ __launch_bounds__(256)
void vdt_kernel(const short* __restrict__ v, const float* __restrict__ d2,
                short* __restrict__ o)
{
    const int t0 = blockIdx.x * 32, d0 = blockIdx.y * 32, b = blockIdx.z;
    const int tx = threadIdx.x & 31, ty = threadIdx.x >> 5;
    __shared__ float tile[32][33];
    for (int s = 0; s < 32; s += 8) {
        int t = t0 + ty + s;
        tile[ty + s][tx] = bf2f(v[((long)b * TT + t) * DD + d0 + tx]) * d2[(long)b * TT + t];
    }
    __syncthreads();
    for (int s = 0; s < 32; s += 8) {
        int d = d0 + ty + s;
        o[((long)b * DD + d) * TT + t0 + tx] = f2bf(tile[tx][ty + s]);
    }
}

// ---------------------------------------------------------------------------
extern "C" void kernel_launch(void* const* d_in, const int* in_sizes, int n_in,
                              void* d_out, int out_size, void* d_ws, size_t ws_size,
                              hipStream_t stream)
{
    (void)in_sizes; (void)n_in; (void)out_size; (void)ws_size;
    const float* x = (const float*)d_in[0];
    const float* W[27];
    for (int i = 1; i < 27; ++i) W[i] = (const float*)d_in[i];
    float* out = (float*)d_out;

    char* ws = (char*)d_ws;
    size_t off = 0;
    auto alloc = [&](size_t bytes) -> void* {
        void* p = ws + off; off += (bytes + 255) & ~(size_t)255; return p;
    };
    short* xb     = (short*)alloc((size_t)MT * DD * 2);          // -> VDT
    short* WcatT  = (short*)alloc((size_t)GLD * DD * 2);
    short* W2catT = (short*)alloc((size_t)8 * DD * 64 * 2);
    short* Gb512  = (short*)alloc((size_t)MT * 512 * 2);
    short* Wob    = (short*)alloc((size_t)DD * DD * 2);
    short* S1b    = (short*)alloc((size_t)MT * DD * 2);          // mvo bf16
    short* VB     = (short*)alloc((size_t)MT * DD * 2);          // v bf16
    short* QGaug  = (short*)alloc((size_t)MT * KAUG * 2);        // | contiguous
    short* QSGaug = (short*)alloc((size_t)MT * KAUG * 2);        // |
    short* KBaug  = (short*)alloc((size_t)MT * KAUG * 2);
    short* KSBaug = (short*)alloc((size_t)MT * KAUG * 2);
    short* CM     = (short*)alloc((size_t)MT * DD * 2);
    short* P      = (short*)alloc((size_t)BB * TT * TT * 2);
    float* d1   = (float*)alloc((size_t)MT * 4);
    float* d1s  = (float*)alloc((size_t)MT * 4);
    float* d2   = (float*)alloc((size_t)MT * 4);
    float* B1T  = (float*)alloc((size_t)RS * MT * 4);            // | contiguous
    float* B1sT = (float*)alloc((size_t)RS * MT * 4);            // | (e_kernel
    float* A2T  = (float*)alloc((size_t)RS * MT * 4);            // |  indexes)
    short* B2T  = (short*)alloc((size_t)RS * MT * 2);
    float* C1   = (float*)alloc((size_t)BB * DD * RS * 4);       // | contiguous
    float* C1s  = (float*)alloc((size_t)BB * DD * RS * 4);       // | (zb paths)
    float* A2tV = (float*)alloc((size_t)BB * RS * DD * 4);
    float* rowsum = (float*)alloc((size_t)MT * 4);               // | zero block
    float* E    = (float*)alloc((size_t)3 * BB * 64 * RS * 4);   // | (rowsum,
    float* hB   = (float*)alloc((size_t)MT * RS * 4);            // |  E, hB)

    short* VDT = xb;        // xb dead after stage-1
    short* cm  = CM;

    const long n4 = (long)MT * DD / 4;
    const int ZN = MT + 3 * BB * 64 * RS + MT * RS;   // rowsum+E+hB (contiguous)

    // --- input/weight conversion (+ zero accumulators) ---
    f2bf_vec_kernel<<<n4 / 256, 256, 0, stream>>>(x, xb, n4);
    ConcatArgs ca;
    {
        const int w1idx[8] = {1, 3, 5, 7, 9, 11, 13, 15};
        for (int s = 0; s < 8; ++s) { ca.p[s] = W[w1idx[s]]; ca.col0[s] = s * 64; ca.wid[s] = 64; }
        const int didx[9] = {18, 19, 20, 21, 22, 23, 24, 25, 26};
        const int dcol[9] = {512, 513, 529, 545, 546, 562, 578, 579, 595};
        const int dwid[9] = {1, 16, 16, 1, 16, 16, 1, 16, 16};
        for (int s = 0; s < 9; ++s) { ca.p[8 + s] = W[didx[s]]; ca.col0[8 + s] = dcol[s]; ca.wid[8 + s] = dwid[s]; }
    }
    concat_w1_kernel<<<GLD, 256, 0, stream>>>(ca, WcatT, rowsum, ZN);
    Ptrs8 p8;
    {
        const int w2idx[8] = {2, 4, 6, 8, 10, 12, 14, 16};
        for (int s = 0; s < 8; ++s) p8.p[s] = W[w2idx[s]];
    }
    concat_w2_kernel<<<dim3(DD / 64, 8), 256, 0, stream>>>(p8, W2catT);
    f2bf_vec_kernel<<<((long)DD * DD / 4) / 256, 256, 0, stream>>>(W[17], Wob, (long)DD * DD / 4);

    // --- stage-1 (SoA scatter epilogue; G never materialized) ---
    gemm_s1<<<dim3(GLD / 128, MT / 128, 1), 512, 0, stream>>>(
        xb, WcatT, Gb512, d1, d1s, d2, B1T, B1sT, A2T, B2T,
        QGaug, QSGaug, KBaug, KSBaug);

    // --- factored skinny reductions: E then C1/C1s/A2tV ---
    e_kernel<<<dim3(16, BB, 3), 256, 0, stream>>>(Gb512, B1T, E);
    c1w_kernel<<<dim3(DD / 64, 3, BB), 256, 0, stream>>>(W2catT, E, C1, A2tV);

    // --- stage-2: one launch, 6 slices ---
    S2A a;
    a.sl[0] = {0, 0, 1, QGaug,  nullptr};   // q*mg
    a.sl[1] = {0, 3, 4, QSGaug, nullptr};   // qs*mgs
    a.sl[2] = {1, 2, 0, KBaug,  d1};        // k*d1 -> aug
    a.sl[3] = {1, 5, 0, KSBaug, d1s};       // ks*d1s -> aug
    a.sl[4] = {3, 6, 0, VB,     nullptr};   // v bf16
    a.sl[5] = {3, 7, 0, S1b,    nullptr};   // mvo bf16
    stage2_kernel<<<dim3(DD / 128, MT / 128, 6), 512, 0, stream>>>(Gb512, W2catT, a);

    // --- vdT from bf16 v ---
    vdt_kernel<<<dim3(TT / 32, DD / 32, BB), 256, 0, stream>>>(VB, d2, VDT);

    // --- zB into aug cols (both paths) ---
    zb_kernel<<<dim3(MT, 2), 256, 0, stream>>>(QGaug, C1);

    // --- fused hm/hs GEMMs + HyperGLU + hB partials -> P, rowsum, hBraw ---
    hmhs_kernel<<<dim3(TT / 128, TT / 128, BB), 256, 0, stream>>>(
        QGaug, QSGaug, KBaug, KSBaug, B2T, P, rowsum, hB);

    // --- context + rank16(raw hB) + deferred iv + mvo -> cm ---
    ctx_kernel<<<dim3(DD / 128, TT / 128, BB), 512, 0, stream>>>(
        P, VDT, S1b, hB, A2tV, rowsum, cm);

    // --- out = cm @ Wo^T ---
    gemm_nt<0><<<dim3(DD / 128, MT / 128, 1), 512, 0, stream>>>(
        cm, Wob, out, DD, DD, DD, DD, 0, 0, 0);
}

// Round 16
// 263.501 us; speedup vs baseline: 1.3369x; 1.3369x over previous
//
#include <hip/hip_runtime.h>
#include <math.h>

#define BB 2
#define TT 2048
#define DD 1024
#define RS 16
#define MT (BB*TT)      // 4096 flattened rows
#define GLD 640         // stage-1 concat output width (611 used, padded)
#define KAUG 1056       // 1024 + 16 (zB/A1) + 16 zero pad; multiple of 32

typedef __attribute__((ext_vector_type(8))) short s16x8;
typedef __attribute__((ext_vector_type(4))) float f32x4;

__device__ __forceinline__ short f2bf(float f) {
    union { float f; unsigned u; } v; v.f = f;
    unsigned r = (v.u + 0x7fffu + ((v.u >> 16) & 1u)) >> 16;
    return (short)r;
}
__device__ __forceinline__ float bf2f(short s) {
    union { unsigned u; float f; } v; v.u = ((unsigned)(unsigned short)s) << 16;
    return v.f;
}

__device__ __forceinline__ void gload16(const void* g, void* l) {
    __builtin_amdgcn_global_load_lds((const __attribute__((address_space(1))) void*)g,
                                     (__attribute__((address_space(3))) void*)l, 16, 0, 0);
}

// XCD-aware block swizzle (all grids are multiples of 8 -> bijective).
__device__ __forceinline__ void xcd_swz(int& bx, int& by, int& bz)
{
    const int gx = gridDim.x, gy = gridDim.y;
    const int n = gx * gy * (int)gridDim.z;
    int flat = (bz * gy + by) * gx + bx;
    const int cpx = n >> 3;
    flat = (flat & 7) * cpx + (flat >> 3);
    bx = flat % gx; by = (flat / gx) % gy; bz = flat / (gx * gy);
}

// ---------------------------------------------------------------------------
// 8-wave (512-thr) pipelined 128x128 NT core, 2M x 4N wave layout.
// r13-proven for single-pass GEMMs (ctx/Wo/s1/stage2): 16 waves/CU at
// 2 blocks/CU hides the stage/barrier latency (m114). acc[4][2] = 32 VGPR.
// Counted vmcnt 2 (depth2) / 4 (depth3); raw s_barrier; granule XOR-swizzle.
// ---------------------------------------------------------------------------
template<int DEPTH>
__device__ __forceinline__ void gemm_core128p(const short* __restrict__ A,
                                              const short* __restrict__ Bt,
                                              int K, int lda, int ldb,
                                              int bi, int bj, short* smem,
                                              f32x4 (&acc)[4][2])
{
    const int tid = threadIdx.x;
    const int wv = tid >> 6, lane = tid & 63;
    const int wr = (wv >> 2) * 64, wc = (wv & 3) * 32;

#pragma unroll
    for (int m = 0; m < 4; ++m)
#pragma unroll
        for (int n = 0; n < 2; ++n) acc[m][n] = (f32x4){0.f, 0.f, 0.f, 0.f};

    const int srow = wv * 16 + (lane >> 2);                // staging row 0..127
    const int sg   = ((lane & 3) ^ ((srow >> 1) & 3)) * 8; // swizzled src granule
    const int frow = lane & 15;
    const int gidx = lane >> 4;
    const int koff = (gidx ^ ((frow >> 1) & 3)) * 8;       // swizzled read offset

    const int nt = K >> 5;
    const long arow = (long)(bi + srow) * lda + sg;
    const long brow = (long)(bj + srow) * ldb + sg;

    auto stage = [&](int t, int q) {
        short* As = smem + q * 8192;
        short* Bs = As + 4096;
        const int k0 = t << 5;
        gload16(A + arow + k0, As + wv*512);
        gload16(Bt + brow + k0, Bs + wv*512);
    };

    stage(0, 0);
    if (nt > 1) stage(1, 1);
    if (DEPTH == 3) { if (nt > 2) stage(2, 2); }

    int q = 0;
    for (int t = 0; t < nt; ++t) {
        const int rem = nt - 1 - t;
        if (DEPTH == 3 && rem >= 2) asm volatile("s_waitcnt vmcnt(4)" ::: "memory");
        else if (rem >= 1)          asm volatile("s_waitcnt vmcnt(2)" ::: "memory");
        else                        asm volatile("s_waitcnt vmcnt(0)" ::: "memory");
        __builtin_amdgcn_s_barrier();          // all waves' tile-t data visible

        const short* As = smem + q * 8192;
        const short* Bs = As + 4096;
        s16x8 af[4], bfr[2];
#pragma unroll
        for (int m = 0; m < 4; ++m)
            af[m] = *(const s16x8*)&As[(wr + m*16 + frow) * 32 + koff];
#pragma unroll
        for (int n = 0; n < 2; ++n)
            bfr[n] = *(const s16x8*)&Bs[(wc + n*16 + frow) * 32 + koff];
        asm volatile("s_waitcnt lgkmcnt(0)" ::: "memory");  // reads in registers
        __builtin_amdgcn_sched_barrier(0);                  // rule-18 fence
        __builtin_amdgcn_s_barrier();          // all waves done READING buf q

        if (t + DEPTH < nt) stage(t + DEPTH, q);  // overwrite safe; overlaps MFMA

#pragma unroll
        for (int m = 0; m < 4; ++m)
#pragma unroll
            for (int n = 0; n < 2; ++n)
                acc[m][n] = __builtin_amdgcn_mfma_f32_16x16x32_bf16(af[m], bfr[n], acc[m][n], 0, 0, 0);
        q = (q == DEPTH - 1) ? 0 : q + 1;
    }
}

// ---------------------------------------------------------------------------
// 4-wave (256-thr) depth-2 core, 2x2 wave layout, acc[4][4]. r11-proven for
// hmhs (59.5us, FETCH 43.7MB); r13's 8-wave variant regressed hmhs to 65us
// (FETCH 55.7MB from L2 thrash with two 512-thr blocks). Used by hmhs ONLY.
// r15 lesson: do NOT fuse per-row rank-16 atomics into this epilogue
// (write-amplification 18->84MB, 2.9x regression).
// ---------------------------------------------------------------------------
__device__ __forceinline__ void gemm_core128p4(const short* __restrict__ A,
                                               const short* __restrict__ Bt,
                                               int K, int lda, int ldb,
                                               int bi, int bj, short* smem,
                                               f32x4 (&acc)[4][4])
{
    const int tid = threadIdx.x;
    const int wv = tid >> 6, lane = tid & 63;
    const int wr = (wv >> 1) * 64, wc = (wv & 1) * 64;

#pragma unroll
    for (int m = 0; m < 4; ++m)
#pragma unroll
        for (int n = 0; n < 4; ++n) acc[m][n] = (f32x4){0.f, 0.f, 0.f, 0.f};

    const int srow = wv * 16 + (lane >> 2);
    const int sg   = ((lane & 3) ^ ((srow >> 1) & 3)) * 8;
    const int frow = lane & 15;
    const int gidx = lane >> 4;
    const int koff = (gidx ^ ((frow >> 1) & 3)) * 8;

    const int nt = K >> 5;
    const long arow = (long)(bi + srow) * lda + sg;
    const long brow = (long)(bj + srow) * ldb + sg;

    auto stage = [&](int t, int q) {
        short* As = smem + q * 8192;
        short* Bs = As + 4096;
        const int k0 = t << 5;
#pragma unroll
        for (int p = 0; p < 2; ++p) {
            gload16(A + arow + (long)p * 64 * lda + k0, As + p*2048 + wv*512);
            gload16(Bt + brow + (long)p * 64 * ldb + k0, Bs + p*2048 + wv*512);
        }
    };

    stage(0, 0);
    if (nt > 1) stage(1, 1);

    int q = 0;
    for (int t = 0; t < nt; ++t) {
        const int rem = nt - 1 - t;
        if (rem >= 1) asm volatile("s_waitcnt vmcnt(4)" ::: "memory");
        else          asm volatile("s_waitcnt vmcnt(0)" ::: "memory");
        __builtin_amdgcn_s_barrier();

        const short* As = smem + q * 8192;
        const short* Bs = As + 4096;
        s16x8 af[4], bfr[4];
#pragma unroll
        for (int m = 0; m < 4; ++m)
            af[m] = *(const s16x8*)&As[(wr + m*16 + frow) * 32 + koff];
#pragma unroll
        for (int n = 0; n < 4; ++n)
            bfr[n] = *(const s16x8*)&Bs[(wc + n*16 + frow) * 32 + koff];
        asm volatile("s_waitcnt lgkmcnt(0)" ::: "memory");
        __builtin_amdgcn_sched_barrier(0);
        __builtin_amdgcn_s_barrier();

        if (t + 2 < nt) stage(t + 2, q);

#pragma unroll
        for (int m = 0; m < 4; ++m)
#pragma unroll
            for (int n = 0; n < 4; ++n)
                acc[m][n] = __builtin_amdgcn_mfma_f32_16x16x32_bf16(af[m], bfr[n], acc[m][n], 0, 0, 0);
        q ^= 1;
    }
}

// Generic batched NT GEMM; STORE 0 = fp32 out, 1 = bf16 out.
template<int STORE>
__global__ __launch_bounds__(512)
void gemm_nt(const short* __restrict__ A, const short* __restrict__ Bt,
             void* __restrict__ Cv, int K, int lda, int ldb, int ldc,
             long sA, long sB, long sC)
{
    int bx = blockIdx.x, by = blockIdx.y, bz = blockIdx.z;
    xcd_swz(bx, by, bz);
    const short* Ab = A  + (long)bz * sA;
    const short* Bb = Bt + (long)bz * sB;
    const int bi = by * 128, bj = bx * 128;
    __shared__ __align__(16) short smem[16384];
    f32x4 acc[4][2];
    gemm_core128p<2>(Ab, Bb, K, lda, ldb, bi, bj, smem, acc);

    const int lane = threadIdx.x & 63, wv = threadIdx.x >> 6;
    const int wr = (wv >> 2) * 64, wc = (wv & 3) * 32;
    const int col0 = lane & 15, row0 = (lane >> 4) * 4;
#pragma unroll
    for (int m = 0; m < 4; ++m)
#pragma unroll
        for (int n = 0; n < 2; ++n)
#pragma unroll
            for (int r = 0; r < 4; ++r) {
                int i = bi + wr + m*16 + row0 + r;
                int j = bj + wc + n*16 + col0;
                if (STORE == 0)
                    ((float*)Cv + (long)bz * sC)[(long)i * ldc + j] = acc[m][n][r];
                else
                    ((short*)Cv + (long)bz * sC)[(long)i * ldc + j] = f2bf(acc[m][n][r]);
            }
}

// ---------------------------------------------------------------------------
// Stage-1: xb @ WcatT^T. Epilogue: cols <512 -> Gb512 bf16 (stage-2 input);
// cols 512..610 scattered directly to SoA generator arrays (G never stored).
// Also zeroes aug pad cols 1040..1055 (at j==512, once per row).
// ---------------------------------------------------------------------------
__global__ __launch_bounds__(512)
void gemm_s1(const short* __restrict__ xb, const short* __restrict__ WcatT,
             short* __restrict__ Gb512,
             float* __restrict__ d1, float* __restrict__ d1s, float* __restrict__ d2,
             float* __restrict__ B1T, float* __restrict__ B1sT, float* __restrict__ A2T,
             short* __restrict__ B2T,
             short* __restrict__ QGaug, short* __restrict__ QSGaug,
             short* __restrict__ KBaug, short* __restrict__ KSBaug)
{
    int bx = blockIdx.x, by = blockIdx.y, bz = blockIdx.z;
    xcd_swz(bx, by, bz);
    const int bi = by * 128, bj = bx * 128;
    __shared__ __align__(16) short smem[16384];
    f32x4 acc[4][2];
    gemm_core128p<2>(xb, WcatT, DD, DD, DD, bi, bj, smem, acc);

    const int lane = threadIdx.x & 63, wv = threadIdx.x >> 6;
    const int wr = (wv >> 2) * 64, wc = (wv & 3) * 32;
    const int col0 = lane & 15, row0 = (lane >> 4) * 4;
#pragma unroll
    for (int m = 0; m < 4; ++m)
#pragma unroll
        for (int n = 0; n < 2; ++n)
#pragma unroll
            for (int r = 0; r < 4; ++r) {
                int i = bi + wr + m*16 + row0 + r;
                int j = bj + wc + n*16 + col0;
                float val = acc[m][n][r];
                if (j < 512) {
                    Gb512[(long)i * 512 + j] = f2bf(val);
                } else if (j == 512) {
                    d1[i] = val;
                    for (int q = 0; q < RS; ++q) {
                        QGaug [(long)i * KAUG + 1040 + q] = 0;
                        QSGaug[(long)i * KAUG + 1040 + q] = 0;
                        KBaug [(long)i * KAUG + 1040 + q] = 0;
                        KSBaug[(long)i * KAUG + 1040 + q] = 0;
                    }
                } else if (j < 529) {
                    KBaug[(long)i * KAUG + 1024 + (j - 513)] = f2bf(val);
                } else if (j < 545) {
                    B1T[(long)(j - 529) * MT + i] = val;
                } else if (j == 545) {
                    d1s[i] = val;
                } else if (j < 562) {
                    KSBaug[(long)i * KAUG + 1024 + (j - 546)] = f2bf(val);
                } else if (j < 578) {
                    B1sT[(long)(j - 562) * MT + i] = val;
                } else if (j == 578) {
                    d2[i] = val;
                } else if (j < 595) {
                    A2T[(long)(j - 579) * MT + i] = val;
                } else if (j < 611) {
                    B2T[(long)(j - 595) * MT + i] = f2bf(val);
                }
            }
}

// ---------------------------------------------------------------------------
// E[kind][b][c][r] = sum_t Gb512[b*TT+t][col0(kind)+c] * BT_kind[r][b*TT+t]
// ---------------------------------------------------------------------------
__global__ __launch_bounds__(256)
void e_kernel(const short* __restrict__ Gb512, const float* __restrict__ BT0,
              float* __restrict__ E)
{
    const int tc = blockIdx.x, b = blockIdx.y, kind = blockIdx.z;
    const int col0 = (kind == 0) ? 128 : (kind == 1) ? 320 : 384;
    const float* BT = BT0 + (size_t)kind * RS * MT;
    const int c = threadIdx.x & 63, rg = threadIdx.x >> 6;
    float acc[4] = {0.f, 0.f, 0.f, 0.f};
    const int t0 = tc * (TT / 16);
#pragma unroll 2
    for (int tt = 0; tt < TT / 16; ++tt) {
        const long gi = (long)b * TT + t0 + tt;
        float g = bf2f(Gb512[gi * 512 + col0 + c]);
#pragma unroll
        for (int q = 0; q < 4; ++q)
            acc[q] = fmaf(g, BT[(long)(rg * 4 + q) * MT + gi], acc[q]);
    }
#pragma unroll
    for (int q = 0; q < 4; ++q)
        atomicAdd(&E[(((long)kind * BB + b) * 64 + c) * RS + rg * 4 + q], acc[q]);
}

// ---------------------------------------------------------------------------
// c1w: C1[kind][b][d][r] = sum_c W2T[s(kind)][d][c] * E[kind][b][c][r]
// kind 2 writes A2tV[b][r][d] layout instead.
// ---------------------------------------------------------------------------
__global__ __launch_bounds__(256)
void c1w_kernel(const short* __restrict__ W2, const float* __restrict__ E,
                float* __restrict__ C1, float* __restrict__ A2tV)
{
    const int d0 = blockIdx.x * 64, kind = blockIdx.y, b = blockIdx.z;
    const int s = (kind == 0) ? 2 : (kind == 1) ? 5 : 6;
    __shared__ float El[64][RS];
    {
        const float* Eb = E + ((long)kind * BB + b) * 64 * RS;
        int q = threadIdx.x;
#pragma unroll
        for (int k = 0; k < 4; ++k) ((float*)El)[q + 256 * k] = Eb[q + 256 * k];
    }
    __syncthreads();
    const int dl = threadIdx.x & 63, rg = threadIdx.x >> 6;
    const int d = d0 + dl;
    const short* wrow = W2 + ((long)s * DD + d) * 64;
    float acc[4] = {0.f, 0.f, 0.f, 0.f};
#pragma unroll
    for (int c8 = 0; c8 < 8; ++c8) {
        s16x8 wv = *(const s16x8*)&wrow[c8 * 8];
#pragma unroll
        for (int u = 0; u < 8; ++u) {
            float w = bf2f(wv[u]);
#pragma unroll
            for (int q = 0; q < 4; ++q)
                acc[q] = fmaf(w, El[c8 * 8 + u][rg * 4 + q], acc[q]);
        }
    }
    if (kind < 2) {
        float* dst = C1 + (size_t)kind * BB * DD * RS;
#pragma unroll
        for (int q = 0; q < 4; ++q)
            dst[((long)b * DD + d) * RS + rg * 4 + q] = acc[q];
    } else {
#pragma unroll
        for (int q = 0; q < 4; ++q)
            A2tV[((long)b * RS + rg * 4 + q) * DD + d] = acc[q];
    }
}

// ---------------------------------------------------------------------------
// hmhs_fused: two sequential 4-wave depth-2 core passes (gate, scale),
// 32 KB LDS, 256 threads (r11/r14-proven config). Epilogue:
// P = fast_softplus(hs) * relu(hm) (bf16, norm deferred), rowsum += hm^2.
// ---------------------------------------------------------------------------
__global__ __launch_bounds__(256)
void hmhs_kernel(const short* __restrict__ QGaug, const short* __restrict__ QSGaug,
                 const short* __restrict__ KBaug, const short* __restrict__ KSBaug,
                 short* __restrict__ P, float* __restrict__ rowsum)
{
    int bx = blockIdx.x, by = blockIdx.y, bz = blockIdx.z;
    xcd_swz(bx, by, bz);
    const int b = bz;
    const int bi = by * 128, bj = bx * 128;
    __shared__ __align__(16) short smem[16384];
    f32x4 acc[4][4], acc2[4][4];
    gemm_core128p4(QGaug  + (long)b * TT * KAUG, KBaug  + (long)b * TT * KAUG,
                   KAUG, KAUG, KAUG, bi, bj, smem, acc);
    gemm_core128p4(QSGaug + (long)b * TT * KAUG, KSBaug + (long)b * TT * KAUG,
                   KAUG, KAUG, KAUG, bi, bj, smem, acc2);

    const int lane = threadIdx.x & 63, wv = threadIdx.x >> 6;
    const int wr = (wv >> 1) * 64, wc = (wv & 1) * 64;
    const int col0 = lane & 15, row0 = (lane >> 4) * 4;
    short* Pb = P + (long)b * TT * TT;

    float ss[4][4];
#pragma unroll
    for (int m = 0; m < 4; ++m)
#pragma unroll
        for (int r = 0; r < 4; ++r) ss[m][r] = 0.f;

#pragma unroll
    for (int m = 0; m < 4; ++m)
#pragma unroll
        for (int n = 0; n < 4; ++n)
#pragma unroll
            for (int r = 0; r < 4; ++r) {
                int i = bi + wr + m*16 + row0 + r;
                int j = bj + wc + n*16 + col0;
                float hmv = acc[m][n][r];
                float sv  = acc2[m][n][r];
                // fast softplus: 2 HW transcendentals (error << bf16 rounding)
                float sp  = fmaxf(sv, 0.f) + __logf(1.f + __expf(-fabsf(sv)));
                Pb[(long)i * TT + j] = f2bf(sp * fmaxf(hmv, 0.f));
                ss[m][r] = fmaf(hmv, hmv, ss[m][r]);
            }

#pragma unroll
    for (int m = 0; m < 4; ++m)
#pragma unroll
        for (int r = 0; r < 4; ++r) {
            float v = ss[m][r];
            v += __shfl_xor(v, 1, 64);
            v += __shfl_xor(v, 2, 64);
            v += __shfl_xor(v, 4, 64);
            v += __shfl_xor(v, 8, 64);
            if (col0 == 0)
                atomicAdd(&rowsum[(long)b * TT + bi + wr + m*16 + row0 + r], v);
        }
}

// ---------------------------------------------------------------------------
// finish: hB[i][r] = inv[i] * sum_j P[i][j] * B2T[r][j]
// ---------------------------------------------------------------------------
__global__ __launch_bounds__(256)
void finish_kernel(const short* __restrict__ P, const short* __restrict__ B2T,
                   const float* __restrict__ rowsum, float* __restrict__ hB)
{
    const int i = blockIdx.x, b = blockIdx.y, tid = threadIdx.x;
    const long gi = (long)b * TT + i;
    const float inv = 1.f / (sqrtf(rowsum[gi]) + 1e-8f);
    const short* Pr = P + ((long)b * TT + i) * TT;
    const long tb = (long)b * TT;
    const int j0 = tid * 8;

    float hb[RS];
#pragma unroll
    for (int r = 0; r < RS; ++r) hb[r] = 0.f;

    s16x8 pv = *(const s16x8*)&Pr[j0];
    float pf[8];
#pragma unroll
    for (int q = 0; q < 8; ++q) pf[q] = bf2f(pv[q]);
#pragma unroll
    for (int r = 0; r < RS; ++r) {
        s16x8 bv = *(const s16x8*)&B2T[(long)r * MT + tb + j0];
#pragma unroll
        for (int q = 0; q < 8; ++q) hb[r] = fmaf(pf[q], bf2f(bv[q]), hb[r]);
    }
#pragma unroll
    for (int r = 0; r < RS; ++r)
#pragma unroll
        for (int off = 32; off; off >>= 1) hb[r] += __shfl_down(hb[r], off, 64);
    __shared__ float red[4][RS];
    if ((tid & 63) == 0)
#pragma unroll
        for (int r = 0; r < RS; ++r) red[tid >> 6][r] = hb[r];
    __syncthreads();
    if (tid < RS)
        hB[gi * RS + tid] = (red[0][tid] + red[1][tid] + red[2][tid] + red[3][tid]) * inv;
}

// ---------------------------------------------------------------------------
// Stage-2 multi-slice GEMM (K=64 per pass).
// mode 0 (GATE):   two passes (sa,sb); out bf16(acc*acc2) at ldc KAUG.
// mode 1 (SCALED): outS bf16(acc*rs[i]) at ldc KAUG.
// mode 3 (BF16):   outS bf16 ldc DD.
// ---------------------------------------------------------------------------
struct S2S { int mode, sa, sb; short* outS; const float* rs; };
struct S2A { S2S sl[6]; };

__global__ __launch_bounds__(512)
void stage2_kernel(const short* __restrict__ Gb, const short* __restrict__ W2,
                   S2A args)
{
    int bx = blockIdx.x, by = blockIdx.y, bz = blockIdx.z;
    xcd_swz(bx, by, bz);
    const S2S sl = args.sl[bz];
    const int bi = by * 128, bj = bx * 128;
    __shared__ __align__(16) short smem[16384];
    f32x4 acc[4][2];
    gemm_core128p<2>(Gb + sl.sa * 64, W2 + (long)sl.sa * DD * 64, 64, 512, 64, bi, bj, smem, acc);
    f32x4 acc2[4][2];
    if (sl.mode == 0)
        gemm_core128p<2>(Gb + sl.sb * 64, W2 + (long)sl.sb * DD * 64, 64, 512, 64, bi, bj, smem, acc2);

    const int lane = threadIdx.x & 63, wv = threadIdx.x >> 6;
    const int wr = (wv >> 2) * 64, wc = (wv & 3) * 32;
    const int col0 = lane & 15, row0 = (lane >> 4) * 4;
#pragma unroll
    for (int m = 0; m < 4; ++m)
#pragma unroll
        for (int n = 0; n < 2; ++n)
#pragma unroll
            for (int r = 0; r < 4; ++r) {
                int i = bi + wr + m*16 + row0 + r;
                int j = bj + wc + n*16 + col0;
                float val = acc[m][n][r];
                if (sl.mode == 0) {
                    sl.outS[(long)i * KAUG + j] = f2bf(val * acc2[m][n][r]);
                } else if (sl.mode == 1) {
                    sl.outS[(long)i * KAUG + j] = f2bf(val * sl.rs[i]);
                } else {
                    sl.outS[(long)i * DD + j] = f2bf(val);
                }
            }
}

// ---------------------------------------------------------------------------
// Context GEMM, fused epilogue: cm = bf16((P@VDT^T * inv[i] + hB@A2tV) * mvo)
// DEPTH=3 (longest K-loop, single accumulator). mvo read as bf16.
// ---------------------------------------------------------------------------
__global__ __launch_bounds__(512)
void ctx_kernel(const short* __restrict__ P, const short* __restrict__ VDT,
                const short* __restrict__ mvo, const float* __restrict__ hB,
                const float* __restrict__ A2tV, const float* __restrict__ rowsum,
                short* __restrict__ cm)
{
    int bx = blockIdx.x, by = blockIdx.y, bz = blockIdx.z;
    xcd_swz(bx, by, bz);
    const int b = bz;
    const int bi = by * 128, bj = bx * 128;
    __shared__ __align__(16) short smem[24576];
    f32x4 acc[4][2];
    gemm_core128p<3>(P + (long)b * TT * TT, VDT + (long)b * DD * TT, TT, TT, TT, bi, bj, smem, acc);

    const int lane = threadIdx.x & 63, wv = threadIdx.x >> 6;
    const int wr = (wv >> 2) * 64, wc = (wv & 3) * 32;
    const int col0 = lane & 15, row0 = (lane >> 4) * 4;
    const float* a2 = A2tV + (long)b * RS * DD;

#pragma unroll
    for (int m = 0; m < 4; ++m)
#pragma unroll
        for (int r = 0; r < 4; ++r) {
            long gi = (long)b * TT + bi + wr + m*16 + row0 + r;
            float iv = 1.f / (sqrtf(rowsum[gi]) + 1e-8f);
#pragma unroll
            for (int n = 0; n < 2; ++n) acc[m][n][r] *= iv;
        }

#pragma unroll
    for (int r16 = 0; r16 < RS; ++r16) {
        float a2v[2];
#pragma unroll
        for (int n = 0; n < 2; ++n)
            a2v[n] = a2[(long)r16 * DD + bj + wc + n*16 + col0];
#pragma unroll
        for (int m = 0; m < 4; ++m)
#pragma unroll
            for (int r = 0; r < 4; ++r) {
                long gi = (long)b * TT + bi + wr + m*16 + row0 + r;
                float hb = hB[gi * RS + r16];
#pragma unroll
                for (int n = 0; n < 2; ++n)
                    acc[m][n][r] = fmaf(hb, a2v[n], acc[m][n][r]);
            }
    }
#pragma unroll
    for (int m = 0; m < 4; ++m)
#pragma unroll
        for (int n = 0; n < 2; ++n)
#pragma unroll
            for (int r = 0; r < 4; ++r) {
                long gi = (long)b * TT + bi + wr + m*16 + row0 + r;
                int j = bj + wc + n*16 + col0;
                cm[gi * DD + j] = f2bf(acc[m][n][r] * bf2f(mvo[gi * DD + j]));
            }
}

// ---------------------------------------------------------------------------
// Weight prep
// ---------------------------------------------------------------------------
struct ConcatArgs { const float* p[17]; int col0[17]; int wid[17]; };

__global__ __launch_bounds__(256)
void concat_w1_kernel(ConcatArgs a, short* __restrict__ WcatT,
                      float* __restrict__ zp, int zn)
{
    const int q = blockIdx.x * 256 + threadIdx.x;
    if (q < zn) zp[q] = 0.f;
    const int n = blockIdx.x;
    int s = -1, c = 0;
    for (int i = 0; i < 17; ++i)
        if (n >= a.col0[i] && n < a.col0[i] + a.wid[i]) { s = i; c = n - a.col0[i]; }
    for (int k = threadIdx.x; k < DD; k += 256)
        WcatT[(long)n * DD + k] = (s < 0) ? (short)0 : f2bf(a.p[s][(long)k * a.wid[s] + c]);
}

struct Ptrs8 { const float* p[8]; };

__global__ __launch_bounds__(256)
void concat_w2_kernel(Ptrs8 a, short* __restrict__ W2catT)
{
    const int s = blockIdx.y, n0 = blockIdx.x * 64;
    const int tx = threadIdx.x & 63, ty = threadIdx.x >> 6;
    __shared__ float t[64][65];
    const float* W2 = a.p[s];
    for (int kk = ty; kk < 64; kk += 4) t[kk][tx] = W2[(long)kk * DD + n0 + tx];
    __syncthreads();
    for (int n = ty; n < 64; n += 4)
        W2catT[((long)s * DD + n0 + n) * 64 + tx] = f2bf(t[tx][n]);
}

__global__ __launch_bounds__(256)
void f2bf_vec_kernel(const float* __restrict__ in, short* __restrict__ o, long n4)
{
    long i = (long)blockIdx.x * 256 + threadIdx.x;
    if (i < n4) {
        float4 v = ((const float4*)in)[i];
        short4 r; r.x = f2bf(v.x); r.y = f2bf(v.y); r.z = f2bf(v.z); r.w = f2bf(v.w);
        ((short4*)o)[i] = r;
    }
}

// zB[i][:] = qg[i][:1024] @ C1[b] (fp32 C1) -> aug cols 1024..1039
__global__ __launch_bounds__(256)
void zb_kernel(short* __restrict__ aug0, const float* __restrict__ C10)
{
    const int gi = blockIdx.x, path = blockIdx.y, b = gi >> 11, tid = threadIdx.x;
    short* aug = aug0 + (size_t)path * MT * KAUG;
    const float* c1 = C10 + (size_t)path * BB * DD * RS + (long)b * DD * RS;
    const short* qrow = aug + (long)gi * KAUG;
    float acc[RS];
#pragma unroll
    for (int r = 0; r < RS; ++r) acc[r] = 0.f;
#pragma unroll
    for (int c = 0; c < 4; ++c) {
        int d = tid + 256 * c;
        float q = bf2f(qrow[d]);
        const float* cr = c1 + (long)d * RS;
#pragma unroll
        for (int r = 0; r < RS; ++r) acc[r] = fmaf(q, cr[r], acc[r]);
    }
#pragma unroll
    for (int r = 0; r < RS; ++r)
#pragma unroll
        for (int off = 32; off; off >>= 1) acc[r] += __shfl_down(acc[r], off, 64);
    __shared__ float red[4][RS];
    if ((tid & 63) == 0)
#pragma unroll
        for (int r = 0; r < RS; ++r) red[tid >> 6][r] = acc[r];
    __syncthreads();
    if (tid < RS)
        aug[(long)gi * KAUG + 1024 + tid] =
            f2bf(red[0][tid] + red[1][tid] + red[2][tid] + red[3][tid]);
}

// ---------------------------------------------------------------------------
// vdT[b][d][t] = bf16(vb[b][t][d] * d2[b*TT+t])   (vb bf16)
// ---------------------------------------------------------------------------
__global__ __launch_bounds__(256)
void vdt_kernel(const short* __restrict__ v, const float* __restrict__ d2,
                short* __restrict__ o)
{
    const int t0 = blockIdx.x * 32, d0 = blockIdx.y * 32, b = blockIdx.z;
    const int tx = threadIdx.x & 31, ty = threadIdx.x >> 5;
    __shared__ float tile[32][33];
    for (int s = 0; s < 32; s += 8) {
        int t = t0 + ty + s;
        tile[ty + s][tx] = bf2f(v[((long)b * TT + t) * DD + d0 + tx]) * d2[(long)b * TT + t];
    }
    __syncthreads();
    for (int s = 0; s < 32; s += 8) {
        int d = d0 + ty + s;
        o[((long)b * DD + d) * TT + t0 + tx] = f2bf(tile[tx][ty + s]);
    }
}

// ---------------------------------------------------------------------------
extern "C" void kernel_launch(void* const* d_in, const int* in_sizes, int n_in,
                              void* d_out, int out_size, void* d_ws, size_t ws_size,
                              hipStream_t stream)
{
    (void)in_sizes; (void)n_in; (void)out_size; (void)ws_size;
    const float* x = (const float*)d_in[0];
    const float* W[27];
    for (int i = 1; i < 27; ++i) W[i] = (const float*)d_in[i];
    float* out = (float*)d_out;

    char* ws = (char*)d_ws;
    size_t off = 0;
    auto alloc = [&](size_t bytes) -> void* {
        void* p = ws + off; off += (bytes + 255) & ~(size_t)255; return p;
    };
    short* xb     = (short*)alloc((size_t)MT * DD * 2);          // -> VDT
    short* WcatT  = (short*)alloc((size_t)GLD * DD * 2);
    short* W2catT = (short*)alloc((size_t)8 * DD * 64 * 2);
    short* Gb512  = (short*)alloc((size_t)MT * 512 * 2);
    short* Wob    = (short*)alloc((size_t)DD * DD * 2);
    short* S1b    = (short*)alloc((size_t)MT * DD * 2);          // mvo bf16
    short* VB     = (short*)alloc((size_t)MT * DD * 2);          // v bf16
    short* QGaug  = (short*)alloc((size_t)MT * KAUG * 2);        // | contiguous
    short* QSGaug = (short*)alloc((size_t)MT * KAUG * 2);        // |
    short* KBaug  = (short*)alloc((size_t)MT * KAUG * 2);
    short* KSBaug = (short*)alloc((size_t)MT * KAUG * 2);
    short* CM     = (short*)alloc((size_t)MT * DD * 2);
    short* P      = (short*)alloc((size_t)BB * TT * TT * 2);
    float* d1   = (float*)alloc((size_t)MT * 4);
    float* d1s  = (float*)alloc((size_t)MT * 4);
    float* d2   = (float*)alloc((size_t)MT * 4);
    float* B1T  = (float*)alloc((size_t)RS * MT * 4);            // | contiguous
    float* B1sT = (float*)alloc((size_t)RS * MT * 4);            // | (e_kernel
    float* A2T  = (float*)alloc((size_t)RS * MT * 4);            // |  indexes)
    short* B2T  = (short*)alloc((size_t)RS * MT * 2);
    float* C1   = (float*)alloc((size_t)BB * DD * RS * 4);       // | contiguous
    float* C1s  = (float*)alloc((size_t)BB * DD * RS * 4);       // | (zb paths)
    float* A2tV = (float*)alloc((size_t)BB * RS * DD * 4);
    float* rowsum = (float*)alloc((size_t)MT * 4);               // | zero block
    float* E    = (float*)alloc((size_t)3 * BB * 64 * RS * 4);   // |
    float* hB   = (float*)alloc((size_t)MT * RS * 4);

    short* VDT = xb;        // xb dead after stage-1
    short* cm  = CM;

    const long n4 = (long)MT * DD / 4;
    const int ZN = MT + 3 * BB * 64 * RS;   // rowsum + E floats (contiguous)

    // --- input/weight conversion (+ zero accumulators) ---
    f2bf_vec_kernel<<<n4 / 256, 256, 0, stream>>>(x, xb, n4);
    ConcatArgs ca;
    {
        const int w1idx[8] = {1, 3, 5, 7, 9, 11, 13, 15};
        for (int s = 0; s < 8; ++s) { ca.p[s] = W[w1idx[s]]; ca.col0[s] = s * 64; ca.wid[s] = 64; }
        const int didx[9] = {18, 19, 20, 21, 22, 23, 24, 25, 26};
        const int dcol[9] = {512, 513, 529, 545, 546, 562, 578, 579, 595};
        const int dwid[9] = {1, 16, 16, 1, 16, 16, 1, 16, 16};
        for (int s = 0; s < 9; ++s) { ca.p[8 + s] = W[didx[s]]; ca.col0[8 + s] = dcol[s]; ca.wid[8 + s] = dwid[s]; }
    }
    concat_w1_kernel<<<GLD, 256, 0, stream>>>(ca, WcatT, rowsum, ZN);
    Ptrs8 p8;
    {
        const int w2idx[8] = {2, 4, 6, 8, 10, 12, 14, 16};
        for (int s = 0; s < 8; ++s) p8.p[s] = W[w2idx[s]];
    }
    concat_w2_kernel<<<dim3(DD / 64, 8), 256, 0, stream>>>(p8, W2catT);
    f2bf_vec_kernel<<<((long)DD * DD / 4) / 256, 256, 0, stream>>>(W[17], Wob, (long)DD * DD / 4);

    // --- stage-1 (SoA scatter epilogue; G never materialized) ---
    gemm_s1<<<dim3(GLD / 128, MT / 128, 1), 512, 0, stream>>>(
        xb, WcatT, Gb512, d1, d1s, d2, B1T, B1sT, A2T, B2T,
        QGaug, QSGaug, KBaug, KSBaug);

    // --- factored skinny reductions: E then C1/C1s/A2tV ---
    e_kernel<<<dim3(16, BB, 3), 256, 0, stream>>>(Gb512, B1T, E);
    c1w_kernel<<<dim3(DD / 64, 3, BB), 256, 0, stream>>>(W2catT, E, C1, A2tV);

    // --- stage-2: one launch, 6 slices ---
    S2A a;
    a.sl[0] = {0, 0, 1, QGaug,  nullptr};   // q*mg
    a.sl[1] = {0, 3, 4, QSGaug, nullptr};   // qs*mgs
    a.sl[2] = {1, 2, 0, KBaug,  d1};        // k*d1 -> aug
    a.sl[3] = {1, 5, 0, KSBaug, d1s};       // ks*d1s -> aug
    a.sl[4] = {3, 6, 0, VB,     nullptr};   // v bf16
    a.sl[5] = {3, 7, 0, S1b,    nullptr};   // mvo bf16
    stage2_kernel<<<dim3(DD / 128, MT / 128, 6), 512, 0, stream>>>(Gb512, W2catT, a);

    // --- vdT from bf16 v ---
    vdt_kernel<<<dim3(TT / 32, DD / 32, BB), 256, 0, stream>>>(VB, d2, VDT);

    // --- zB into aug cols (both paths) ---
    zb_kernel<<<dim3(MT, 2), 256, 0, stream>>>(QGaug, C1);

    // --- fused hm/hs GEMMs + HyperGLU -> P, rowsum (4-wave core) ---
    hmhs_kernel<<<dim3(TT / 128, TT / 128, BB), 256, 0, stream>>>(
        QGaug, QSGaug, KBaug, KSBaug, P, rowsum);

    // --- finish: hB (inv folded) ---
    finish_kernel<<<dim3(TT, BB), 256, 0, stream>>>(P, B2T, rowsum, hB);

    // --- context + inv + rank16 + mvo -> cm ---
    ctx_kernel<<<dim3(DD / 128, TT / 128, BB), 512, 0, stream>>>(
        P, VDT, S1b, hB, A2tV, rowsum, cm);

    // --- out = cm @ Wo^T ---
    gemm_nt<0><<<dim3(DD / 128, MT / 128, 1), 512, 0, stream>>>(
        cm, Wob, out, DD, DD, DD, DD, 0, 0, 0);
}

// Round 17
// 260.743 us; speedup vs baseline: 1.3510x; 1.0106x over previous
//
#include <hip/hip_runtime.h>
#include <math.h>

#define BB 2
#define TT 2048
#define DD 1024
#define RS 16
#define MT (BB*TT)      // 4096 flattened rows
#define GLD 640         // stage-1 concat output width (611 used, padded)
#define KAUG 1088       // 1024 + 16 (zB/A1) + 48 zero pad; multiple of 64

typedef __attribute__((ext_vector_type(8))) short s16x8;
typedef __attribute__((ext_vector_type(4))) float f32x4;

__device__ __forceinline__ short f2bf(float f) {
    union { float f; unsigned u; } v; v.f = f;
    unsigned r = (v.u + 0x7fffu + ((v.u >> 16) & 1u)) >> 16;
    return (short)r;
}
__device__ __forceinline__ float bf2f(short s) {
    union { unsigned u; float f; } v; v.u = ((unsigned)(unsigned short)s) << 16;
    return v.f;
}

__device__ __forceinline__ void gload16(const void* g, void* l) {
    __builtin_amdgcn_global_load_lds((const __attribute__((address_space(1))) void*)g,
                                     (__attribute__((address_space(3))) void*)l, 16, 0, 0);
}

// XCD-aware block swizzle (all grids are multiples of 8 -> bijective).
__device__ __forceinline__ void xcd_swz(int& bx, int& by, int& bz)
{
    const int gx = gridDim.x, gy = gridDim.y;
    const int n = gx * gy * (int)gridDim.z;
    int flat = (bz * gy + by) * gx + bx;
    const int cpx = n >> 3;
    flat = (flat & 7) * cpx + (flat >> 3);
    bx = flat % gx; by = (flat / gx) % gy; bz = flat / (gx * gy);
}

// ---------------------------------------------------------------------------
// 8-wave (512-thr) pipelined 128x128 NT core (BK=32), 2M x 4N wave layout.
// r13-proven for single-pass GEMMs (ctx/Wo/s1/stage2). acc[4][2] = 32 VGPR.
// Counted vmcnt 2 (depth2) / 4 (depth3); raw s_barrier; granule XOR-swizzle.
// ---------------------------------------------------------------------------
template<int DEPTH>
__device__ __forceinline__ void gemm_core128p(const short* __restrict__ A,
                                              const short* __restrict__ Bt,
                                              int K, int lda, int ldb,
                                              int bi, int bj, short* smem,
                                              f32x4 (&acc)[4][2])
{
    const int tid = threadIdx.x;
    const int wv = tid >> 6, lane = tid & 63;
    const int wr = (wv >> 2) * 64, wc = (wv & 3) * 32;

#pragma unroll
    for (int m = 0; m < 4; ++m)
#pragma unroll
        for (int n = 0; n < 2; ++n) acc[m][n] = (f32x4){0.f, 0.f, 0.f, 0.f};

    const int srow = wv * 16 + (lane >> 2);                // staging row 0..127
    const int sg   = ((lane & 3) ^ ((srow >> 1) & 3)) * 8; // swizzled src granule
    const int frow = lane & 15;
    const int gidx = lane >> 4;
    const int koff = (gidx ^ ((frow >> 1) & 3)) * 8;       // swizzled read offset

    const int nt = K >> 5;
    const long arow = (long)(bi + srow) * lda + sg;
    const long brow = (long)(bj + srow) * ldb + sg;

    auto stage = [&](int t, int q) {
        short* As = smem + q * 8192;
        short* Bs = As + 4096;
        const int k0 = t << 5;
        gload16(A + arow + k0, As + wv*512);
        gload16(Bt + brow + k0, Bs + wv*512);
    };

    stage(0, 0);
    if (nt > 1) stage(1, 1);
    if (DEPTH == 3) { if (nt > 2) stage(2, 2); }

    int q = 0;
    for (int t = 0; t < nt; ++t) {
        const int rem = nt - 1 - t;
        if (DEPTH == 3 && rem >= 2) asm volatile("s_waitcnt vmcnt(4)" ::: "memory");
        else if (rem >= 1)          asm volatile("s_waitcnt vmcnt(2)" ::: "memory");
        else                        asm volatile("s_waitcnt vmcnt(0)" ::: "memory");
        __builtin_amdgcn_s_barrier();          // all waves' tile-t data visible

        const short* As = smem + q * 8192;
        const short* Bs = As + 4096;
        s16x8 af[4], bfr[2];
#pragma unroll
        for (int m = 0; m < 4; ++m)
            af[m] = *(const s16x8*)&As[(wr + m*16 + frow) * 32 + koff];
#pragma unroll
        for (int n = 0; n < 2; ++n)
            bfr[n] = *(const s16x8*)&Bs[(wc + n*16 + frow) * 32 + koff];
        asm volatile("s_waitcnt lgkmcnt(0)" ::: "memory");  // reads in registers
        __builtin_amdgcn_sched_barrier(0);                  // rule-18 fence
        __builtin_amdgcn_s_barrier();          // all waves done READING buf q

        if (t + DEPTH < nt) stage(t + DEPTH, q);  // overwrite safe; overlaps MFMA

#pragma unroll
        for (int m = 0; m < 4; ++m)
#pragma unroll
            for (int n = 0; n < 2; ++n)
                acc[m][n] = __builtin_amdgcn_mfma_f32_16x16x32_bf16(af[m], bfr[n], acc[m][n], 0, 0, 0);
        q = (q == DEPTH - 1) ? 0 : q + 1;
    }
}

// ---------------------------------------------------------------------------
// 4-wave (256-thr) BK=64 depth-2 core, 2x2 wave layout, acc[4][4].
// hmhs is grid-limited at 2 blocks/CU -> LDS is free up to 80KB: 64KB here
// (2 bufs x (16KB A + 16KB B)) halves the barrier count (17 tiles vs 33)
// and doubles MFMA per barrier-pair to 32, with NO occupancy loss (unlike
// r6/r10/r12 which shrank occupancy or grew traffic).
// Swizzle: 8 granules/row; phys = glog ^ (row&7); inverse on global source.
// Read conflict: 2-way (free, m136). Tile split into two k-sub-steps to
// cap fragment liveness at 32 VGPR; buffer-release barrier after LAST read.
// ---------------------------------------------------------------------------
__device__ __forceinline__ void gemm_core128_bk64(const short* __restrict__ A,
                                                  const short* __restrict__ Bt,
                                                  int K, int lda, int ldb,
                                                  int bi, int bj, short* smem,
                                                  f32x4 (&acc)[4][4])
{
    const int tid = threadIdx.x;
    const int wv = tid >> 6, lane = tid & 63;
    const int wr = (wv >> 1) * 64, wc = (wv & 1) * 64;

#pragma unroll
    for (int m = 0; m < 4; ++m)
#pragma unroll
        for (int n = 0; n < 4; ++n) acc[m][n] = (f32x4){0.f, 0.f, 0.f, 0.f};

    const int rloc  = lane >> 3;          // 0..7 row within an 8-row group
    const int gphys = lane & 7;           // physical granule this lane writes
    const int frow  = lane & 15;
    const int gsub  = lane >> 4;          // 0..3 logical sub-granule (ks=0)

    const int nt = K >> 6;                // 64-wide K tiles

    // stage tile t into buffer q: 4 A-loads + 4 B-loads per lane
    auto stage = [&](int t, int q) {
        short* As = smem + q * 16384;     // 32KB buffer: A 8192 sh + B 8192 sh
        short* Bs = As + 8192;
        const int k0 = t << 6;
#pragma unroll
        for (int p = 0; p < 4; ++p) {
            const int row = p*32 + wv*8 + rloc;
            const int src = ((gphys ^ (row & 7)) * 8);   // inverse swizzle
            gload16(A  + (long)(bi + row) * lda + k0 + src, As + (p*32 + wv*8) * 64);
            gload16(Bt + (long)(bj + row) * ldb + k0 + src, Bs + (p*32 + wv*8) * 64);
        }
    };

    stage(0, 0);
    if (nt > 1) stage(1, 1);

    int q = 0;
    for (int t = 0; t < nt; ++t) {
        if (t + 1 < nt) asm volatile("s_waitcnt vmcnt(8)" ::: "memory");
        else            asm volatile("s_waitcnt vmcnt(0)" ::: "memory");
        __builtin_amdgcn_s_barrier();          // tile-t data visible

        const short* As = smem + q * 16384;
        const short* Bs = As + 8192;

        // ---- k-sub-step 0 (cols 0..31 of the tile) ----
        {
            s16x8 af[4], bfr[4];
#pragma unroll
            for (int m = 0; m < 4; ++m) {
                const int row = wr + m*16 + frow;
                af[m] = *(const s16x8*)&As[row*64 + ((gsub ^ (row & 7)) * 8)];
            }
#pragma unroll
            for (int n = 0; n < 4; ++n) {
                const int row = wc + n*16 + frow;
                bfr[n] = *(const s16x8*)&Bs[row*64 + ((gsub ^ (row & 7)) * 8)];
            }
            asm volatile("s_waitcnt lgkmcnt(0)" ::: "memory");
            __builtin_amdgcn_sched_barrier(0);
#pragma unroll
            for (int m = 0; m < 4; ++m)
#pragma unroll
                for (int n = 0; n < 4; ++n)
                    acc[m][n] = __builtin_amdgcn_mfma_f32_16x16x32_bf16(af[m], bfr[n], acc[m][n], 0, 0, 0);
        }
        // ---- k-sub-step 1 (cols 32..63) ----
        {
            s16x8 af[4], bfr[4];
#pragma unroll
            for (int m = 0; m < 4; ++m) {
                const int row = wr + m*16 + frow;
                af[m] = *(const s16x8*)&As[row*64 + (((gsub + 4) ^ (row & 7)) * 8)];
            }
#pragma unroll
            for (int n = 0; n < 4; ++n) {
                const int row = wc + n*16 + frow;
                bfr[n] = *(const s16x8*)&Bs[row*64 + (((gsub + 4) ^ (row & 7)) * 8)];
            }
            asm volatile("s_waitcnt lgkmcnt(0)" ::: "memory");
            __builtin_amdgcn_sched_barrier(0);
            __builtin_amdgcn_s_barrier();      // all waves done READING buf q

            if (t + 2 < nt) stage(t + 2, q);   // overwrite safe; overlaps MFMA

#pragma unroll
            for (int m = 0; m < 4; ++m)
#pragma unroll
                for (int n = 0; n < 4; ++n)
                    acc[m][n] = __builtin_amdgcn_mfma_f32_16x16x32_bf16(af[m], bfr[n], acc[m][n], 0, 0, 0);
        }
        q ^= 1;
    }
}

// Generic batched NT GEMM; STORE 0 = fp32 out, 1 = bf16 out.
template<int STORE>
__global__ __launch_bounds__(512)
void gemm_nt(const short* __restrict__ A, const short* __restrict__ Bt,
             void* __restrict__ Cv, int K, int lda, int ldb, int ldc,
             long sA, long sB, long sC)
{
    int bx = blockIdx.x, by = blockIdx.y, bz = blockIdx.z;
    xcd_swz(bx, by, bz);
    const short* Ab = A  + (long)bz * sA;
    const short* Bb = Bt + (long)bz * sB;
    const int bi = by * 128, bj = bx * 128;
    __shared__ __align__(16) short smem[16384];
    f32x4 acc[4][2];
    gemm_core128p<2>(Ab, Bb, K, lda, ldb, bi, bj, smem, acc);

    const int lane = threadIdx.x & 63, wv = threadIdx.x >> 6;
    const int wr = (wv >> 2) * 64, wc = (wv & 3) * 32;
    const int col0 = lane & 15, row0 = (lane >> 4) * 4;
#pragma unroll
    for (int m = 0; m < 4; ++m)
#pragma unroll
        for (int n = 0; n < 2; ++n)
#pragma unroll
            for (int r = 0; r < 4; ++r) {
                int i = bi + wr + m*16 + row0 + r;
                int j = bj + wc + n*16 + col0;
                if (STORE == 0)
                    ((float*)Cv + (long)bz * sC)[(long)i * ldc + j] = acc[m][n][r];
                else
                    ((short*)Cv + (long)bz * sC)[(long)i * ldc + j] = f2bf(acc[m][n][r]);
            }
}

// ---------------------------------------------------------------------------
// Stage-1: xb @ WcatT^T. Epilogue: cols <512 -> Gb512 bf16 (stage-2 input);
// cols 512..610 scattered directly to SoA generator arrays (G never stored).
// Also zeroes aug pad cols 1040..1087 (at j==512, once per row).
// ---------------------------------------------------------------------------
__global__ __launch_bounds__(512)
void gemm_s1(const short* __restrict__ xb, const short* __restrict__ WcatT,
             short* __restrict__ Gb512,
             float* __restrict__ d1, float* __restrict__ d1s, float* __restrict__ d2,
             float* __restrict__ B1T, float* __restrict__ B1sT, float* __restrict__ A2T,
             short* __restrict__ B2T,
             short* __restrict__ QGaug, short* __restrict__ QSGaug,
             short* __restrict__ KBaug, short* __restrict__ KSBaug)
{
    int bx = blockIdx.x, by = blockIdx.y, bz = blockIdx.z;
    xcd_swz(bx, by, bz);
    const int bi = by * 128, bj = bx * 128;
    __shared__ __align__(16) short smem[16384];
    f32x4 acc[4][2];
    gemm_core128p<2>(xb, WcatT, DD, DD, DD, bi, bj, smem, acc);

    const int lane = threadIdx.x & 63, wv = threadIdx.x >> 6;
    const int wr = (wv >> 2) * 64, wc = (wv & 3) * 32;
    const int col0 = lane & 15, row0 = (lane >> 4) * 4;
#pragma unroll
    for (int m = 0; m < 4; ++m)
#pragma unroll
        for (int n = 0; n < 2; ++n)
#pragma unroll
            for (int r = 0; r < 4; ++r) {
                int i = bi + wr + m*16 + row0 + r;
                int j = bj + wc + n*16 + col0;
                float val = acc[m][n][r];
                if (j < 512) {
                    Gb512[(long)i * 512 + j] = f2bf(val);
                } else if (j == 512) {
                    d1[i] = val;
                    for (int q = 0; q < KAUG - 1040; ++q) {
                        QGaug [(long)i * KAUG + 1040 + q] = 0;
                        QSGaug[(long)i * KAUG + 1040 + q] = 0;
                        KBaug [(long)i * KAUG + 1040 + q] = 0;
                        KSBaug[(long)i * KAUG + 1040 + q] = 0;
                    }
                } else if (j < 529) {
                    KBaug[(long)i * KAUG + 1024 + (j - 513)] = f2bf(val);
                } else if (j < 545) {
                    B1T[(long)(j - 529) * MT + i] = val;
                } else if (j == 545) {
                    d1s[i] = val;
                } else if (j < 562) {
                    KSBaug[(long)i * KAUG + 1024 + (j - 546)] = f2bf(val);
                } else if (j < 578) {
                    B1sT[(long)(j - 562) * MT + i] = val;
                } else if (j == 578) {
                    d2[i] = val;
                } else if (j < 595) {
                    A2T[(long)(j - 579) * MT + i] = val;
                } else if (j < 611) {
                    B2T[(long)(j - 595) * MT + i] = f2bf(val);
                }
            }
}

// ---------------------------------------------------------------------------
// E[kind][b][c][r] = sum_t Gb512[b*TT+t][col0(kind)+c] * BT_kind[r][b*TT+t]
// ---------------------------------------------------------------------------
__global__ __launch_bounds__(256)
void e_kernel(const short* __restrict__ Gb512, const float* __restrict__ BT0,
              float* __restrict__ E)
{
    const int tc = blockIdx.x, b = blockIdx.y, kind = blockIdx.z;
    const int col0 = (kind == 0) ? 128 : (kind == 1) ? 320 : 384;
    const float* BT = BT0 + (size_t)kind * RS * MT;
    const int c = threadIdx.x & 63, rg = threadIdx.x >> 6;
    float acc[4] = {0.f, 0.f, 0.f, 0.f};
    const int t0 = tc * (TT / 16);
#pragma unroll 2
    for (int tt = 0; tt < TT / 16; ++tt) {
        const long gi = (long)b * TT + t0 + tt;
        float g = bf2f(Gb512[gi * 512 + col0 + c]);
#pragma unroll
        for (int q = 0; q < 4; ++q)
            acc[q] = fmaf(g, BT[(long)(rg * 4 + q) * MT + gi], acc[q]);
    }
#pragma unroll
    for (int q = 0; q < 4; ++q)
        atomicAdd(&E[(((long)kind * BB + b) * 64 + c) * RS + rg * 4 + q], acc[q]);
}

// ---------------------------------------------------------------------------
// c1w: C1[kind][b][d][r] = sum_c W2T[s(kind)][d][c] * E[kind][b][c][r]
// kind 2 writes A2tV[b][r][d] layout instead.
// ---------------------------------------------------------------------------
__global__ __launch_bounds__(256)
void c1w_kernel(const short* __restrict__ W2, const float* __restrict__ E,
                float* __restrict__ C1, float* __restrict__ A2tV)
{
    const int d0 = blockIdx.x * 64, kind = blockIdx.y, b = blockIdx.z;
    const int s = (kind == 0) ? 2 : (kind == 1) ? 5 : 6;
    __shared__ float El[64][RS];
    {
        const float* Eb = E + ((long)kind * BB + b) * 64 * RS;
        int q = threadIdx.x;
#pragma unroll
        for (int k = 0; k < 4; ++k) ((float*)El)[q + 256 * k] = Eb[q + 256 * k];
    }
    __syncthreads();
    const int dl = threadIdx.x & 63, rg = threadIdx.x >> 6;
    const int d = d0 + dl;
    const short* wrow = W2 + ((long)s * DD + d) * 64;
    float acc[4] = {0.f, 0.f, 0.f, 0.f};
#pragma unroll
    for (int c8 = 0; c8 < 8; ++c8) {
        s16x8 wv = *(const s16x8*)&wrow[c8 * 8];
#pragma unroll
        for (int u = 0; u < 8; ++u) {
            float w = bf2f(wv[u]);
#pragma unroll
            for (int q = 0; q < 4; ++q)
                acc[q] = fmaf(w, El[c8 * 8 + u][rg * 4 + q], acc[q]);
        }
    }
    if (kind < 2) {
        float* dst = C1 + (size_t)kind * BB * DD * RS;
#pragma unroll
        for (int q = 0; q < 4; ++q)
            dst[((long)b * DD + d) * RS + rg * 4 + q] = acc[q];
    } else {
#pragma unroll
        for (int q = 0; q < 4; ++q)
            A2tV[((long)b * RS + rg * 4 + q) * DD + d] = acc[q];
    }
}

// ---------------------------------------------------------------------------
// hmhs_fused: two sequential 4-wave BK=64 depth-2 core passes (gate, scale),
// 64 KB LDS, 256 threads (grid-limited 2 blocks/CU -> LDS free). Epilogue:
// P = fast_softplus(hs) * relu(hm) (bf16, norm deferred), rowsum += hm^2.
// r15 lesson: no per-row rank-16 atomics in this epilogue.
// ---------------------------------------------------------------------------
__global__ __launch_bounds__(256)
void hmhs_kernel(const short* __restrict__ QGaug, const short* __restrict__ QSGaug,
                 const short* __restrict__ KBaug, const short* __restrict__ KSBaug,
                 short* __restrict__ P, float* __restrict__ rowsum)
{
    int bx = blockIdx.x, by = blockIdx.y, bz = blockIdx.z;
    xcd_swz(bx, by, bz);
    const int b = bz;
    const int bi = by * 128, bj = bx * 128;
    __shared__ __align__(16) short smem[32768];   // 64 KB: 2 x (16KB A + 16KB B)
    f32x4 acc[4][4], acc2[4][4];
    gemm_core128_bk64(QGaug  + (long)b * TT * KAUG, KBaug  + (long)b * TT * KAUG,
                      KAUG, KAUG, KAUG, bi, bj, smem, acc);
    gemm_core128_bk64(QSGaug + (long)b * TT * KAUG, KSBaug + (long)b * TT * KAUG,
                      KAUG, KAUG, KAUG, bi, bj, smem, acc2);

    const int lane = threadIdx.x & 63, wv = threadIdx.x >> 6;
    const int wr = (wv >> 1) * 64, wc = (wv & 1) * 64;
    const int col0 = lane & 15, row0 = (lane >> 4) * 4;
    short* Pb = P + (long)b * TT * TT;

    float ss[4][4];
#pragma unroll
    for (int m = 0; m < 4; ++m)
#pragma unroll
        for (int r = 0; r < 4; ++r) ss[m][r] = 0.f;

#pragma unroll
    for (int m = 0; m < 4; ++m)
#pragma unroll
        for (int n = 0; n < 4; ++n)
#pragma unroll
            for (int r = 0; r < 4; ++r) {
                int i = bi + wr + m*16 + row0 + r;
                int j = bj + wc + n*16 + col0;
                float hmv = acc[m][n][r];
                float sv  = acc2[m][n][r];
                // fast softplus: 2 HW transcendentals (error << bf16 rounding)
                float sp  = fmaxf(sv, 0.f) + __logf(1.f + __expf(-fabsf(sv)));
                Pb[(long)i * TT + j] = f2bf(sp * fmaxf(hmv, 0.f));
                ss[m][r] = fmaf(hmv, hmv, ss[m][r]);
            }

#pragma unroll
    for (int m = 0; m < 4; ++m)
#pragma unroll
        for (int r = 0; r < 4; ++r) {
            float v = ss[m][r];
            v += __shfl_xor(v, 1, 64);
            v += __shfl_xor(v, 2, 64);
            v += __shfl_xor(v, 4, 64);
            v += __shfl_xor(v, 8, 64);
            if (col0 == 0)
                atomicAdd(&rowsum[(long)b * TT + bi + wr + m*16 + row0 + r], v);
        }
}

// ---------------------------------------------------------------------------
// finish: hB[i][r] = inv[i] * sum_j P[i][j] * B2T[r][j]
// ---------------------------------------------------------------------------
__global__ __launch_bounds__(256)
void finish_kernel(const short* __restrict__ P, const short* __restrict__ B2T,
                   const float* __restrict__ rowsum, float* __restrict__ hB)
{
    const int i = blockIdx.x, b = blockIdx.y, tid = threadIdx.x;
    const long gi = (long)b * TT + i;
    const float inv = 1.f / (sqrtf(rowsum[gi]) + 1e-8f);
    const short* Pr = P + ((long)b * TT + i) * TT;
    const long tb = (long)b * TT;
    const int j0 = tid * 8;

    float hb[RS];
#pragma unroll
    for (int r = 0; r < RS; ++r) hb[r] = 0.f;

    s16x8 pv = *(const s16x8*)&Pr[j0];
    float pf[8];
#pragma unroll
    for (int q = 0; q < 8; ++q) pf[q] = bf2f(pv[q]);
#pragma unroll
    for (int r = 0; r < RS; ++r) {
        s16x8 bv = *(const s16x8*)&B2T[(long)r * MT + tb + j0];
#pragma unroll
        for (int q = 0; q < 8; ++q) hb[r] = fmaf(pf[q], bf2f(bv[q]), hb[r]);
    }
#pragma unroll
    for (int r = 0; r < RS; ++r)
#pragma unroll
        for (int off = 32; off; off >>= 1) hb[r] += __shfl_down(hb[r], off, 64);
    __shared__ float red[4][RS];
    if ((tid & 63) == 0)
#pragma unroll
        for (int r = 0; r < RS; ++r) red[tid >> 6][r] = hb[r];
    __syncthreads();
    if (tid < RS)
        hB[gi * RS + tid] = (red[0][tid] + red[1][tid] + red[2][tid] + red[3][tid]) * inv;
}

// ---------------------------------------------------------------------------
// Stage-2 multi-slice GEMM (K=64 per pass).
// mode 0 (GATE):   two passes (sa,sb); out bf16(acc*acc2) at ldc KAUG.
// mode 1 (SCALED): outS bf16(acc*rs[i]) at ldc KAUG.
// mode 3 (BF16):   outS bf16 ldc DD.
// ---------------------------------------------------------------------------
struct S2S { int mode, sa, sb; short* outS; const float* rs; };
struct S2A { S2S sl[6]; };

__global__ __launch_bounds__(512)
void stage2_kernel(const short* __restrict__ Gb, const short* __restrict__ W2,
                   S2A args)
{
    int bx = blockIdx.x, by = blockIdx.y, bz = blockIdx.z;
    xcd_swz(bx, by, bz);
    const S2S sl = args.sl[bz];
    const int bi = by * 128, bj = bx * 128;
    __shared__ __align__(16) short smem[16384];
    f32x4 acc[4][2];
    gemm_core128p<2>(Gb + sl.sa * 64, W2 + (long)sl.sa * DD * 64, 64, 512, 64, bi, bj, smem, acc);
    f32x4 acc2[4][2];
    if (sl.mode == 0)
        gemm_core128p<2>(Gb + sl.sb * 64, W2 + (long)sl.sb * DD * 64, 64, 512, 64, bi, bj, smem, acc2);

    const int lane = threadIdx.x & 63, wv = threadIdx.x >> 6;
    const int wr = (wv >> 2) * 64, wc = (wv & 3) * 32;
    const int col0 = lane & 15, row0 = (lane >> 4) * 4;
#pragma unroll
    for (int m = 0; m < 4; ++m)
#pragma unroll
        for (int n = 0; n < 2; ++n)
#pragma unroll
            for (int r = 0; r < 4; ++r) {
                int i = bi + wr + m*16 + row0 + r;
                int j = bj + wc + n*16 + col0;
                float val = acc[m][n][r];
                if (sl.mode == 0) {
                    sl.outS[(long)i * KAUG + j] = f2bf(val * acc2[m][n][r]);
                } else if (sl.mode == 1) {
                    sl.outS[(long)i * KAUG + j] = f2bf(val * sl.rs[i]);
                } else {
                    sl.outS[(long)i * DD + j] = f2bf(val);
                }
            }
}

// ---------------------------------------------------------------------------
// Context GEMM, fused epilogue: cm = bf16((P@VDT^T * inv[i] + hB@A2tV) * mvo)
// DEPTH=3 (longest K-loop, single accumulator). mvo read as bf16.
// ---------------------------------------------------------------------------
__global__ __launch_bounds__(512)
void ctx_kernel(const short* __restrict__ P, const short* __restrict__ VDT,
                const short* __restrict__ mvo, const float* __restrict__ hB,
                const float* __restrict__ A2tV, const float* __restrict__ rowsum,
                short* __restrict__ cm)
{
    int bx = blockIdx.x, by = blockIdx.y, bz = blockIdx.z;
    xcd_swz(bx, by, bz);
    const int b = bz;
    const int bi = by * 128, bj = bx * 128;
    __shared__ __align__(16) short smem[24576];
    f32x4 acc[4][2];
    gemm_core128p<3>(P + (long)b * TT * TT, VDT + (long)b * DD * TT, TT, TT, TT, bi, bj, smem, acc);

    const int lane = threadIdx.x & 63, wv = threadIdx.x >> 6;
    const int wr = (wv >> 2) * 64, wc = (wv & 3) * 32;
    const int col0 = lane & 15, row0 = (lane >> 4) * 4;
    const float* a2 = A2tV + (long)b * RS * DD;

#pragma unroll
    for (int m = 0; m < 4; ++m)
#pragma unroll
        for (int r = 0; r < 4; ++r) {
            long gi = (long)b * TT + bi + wr + m*16 + row0 + r;
            float iv = 1.f / (sqrtf(rowsum[gi]) + 1e-8f);
#pragma unroll
            for (int n = 0; n < 2; ++n) acc[m][n][r] *= iv;
        }

#pragma unroll
    for (int r16 = 0; r16 < RS; ++r16) {
        float a2v[2];
#pragma unroll
        for (int n = 0; n < 2; ++n)
            a2v[n] = a2[(long)r16 * DD + bj + wc + n*16 + col0];
#pragma unroll
        for (int m = 0; m < 4; ++m)
#pragma unroll
            for (int r = 0; r < 4; ++r) {
                long gi = (long)b * TT + bi + wr + m*16 + row0 + r;
                float hb = hB[gi * RS + r16];
#pragma unroll
                for (int n = 0; n < 2; ++n)
                    acc[m][n][r] = fmaf(hb, a2v[n], acc[m][n][r]);
            }
    }
#pragma unroll
    for (int m = 0; m < 4; ++m)
#pragma unroll
        for (int n = 0; n < 2; ++n)
#pragma unroll
            for (int r = 0; r < 4; ++r) {
                long gi = (long)b * TT + bi + wr + m*16 + row0 + r;
                int j = bj + wc + n*16 + col0;
                cm[gi * DD + j] = f2bf(acc[m][n][r] * bf2f(mvo[gi * DD + j]));
            }
}

// ---------------------------------------------------------------------------
// Weight prep
// ---------------------------------------------------------------------------
struct ConcatArgs { const float* p[17]; int col0[17]; int wid[17]; };

__global__ __launch_bounds__(256)
void concat_w1_kernel(ConcatArgs a, short* __restrict__ WcatT,
                      float* __restrict__ zp, int zn)
{
    const int q = blockIdx.x * 256 + threadIdx.x;
    if (q < zn) zp[q] = 0.f;
    const int n = blockIdx.x;
    int s = -1, c = 0;
    for (int i = 0; i < 17; ++i)
        if (n >= a.col0[i] && n < a.col0[i] + a.wid[i]) { s = i; c = n - a.col0[i]; }
    for (int k = threadIdx.x; k < DD; k += 256)
        WcatT[(long)n * DD + k] = (s < 0) ? (short)0 : f2bf(a.p[s][(long)k * a.wid[s] + c]);
}

struct Ptrs8 { const float* p[8]; };

__global__ __launch_bounds__(256)
void concat_w2_kernel(Ptrs8 a, short* __restrict__ W2catT)
{
    const int s = blockIdx.y, n0 = blockIdx.x * 64;
    const int tx = threadIdx.x & 63, ty = threadIdx.x >> 6;
    __shared__ float t[64][65];
    const float* W2 = a.p[s];
    for (int kk = ty; kk < 64; kk += 4) t[kk][tx] = W2[(long)kk * DD + n0 + tx];
    __syncthreads();
    for (int n = ty; n < 64; n += 4)
        W2catT[((long)s * DD + n0 + n) * 64 + tx] = f2bf(t[tx][n]);
}

__global__ __launch_bounds__(256)
void f2bf_vec_kernel(const float* __restrict__ in, short* __restrict__ o, long n4)
{
    long i = (long)blockIdx.x * 256 + threadIdx.x;
    if (i < n4) {
        float4 v = ((const float4*)in)[i];
        short4 r; r.x = f2bf(v.x); r.y = f2bf(v.y); r.z = f2bf(v.z); r.w = f2bf(v.w);
        ((short4*)o)[i] = r;
    }
}

// zB[i][:] = qg[i][:1024] @ C1[b] (fp32 C1) -> aug cols 1024..1039
__global__ __launch_bounds__(256)
void zb_kernel(short* __restrict__ aug0, const float* __restrict__ C10)
{
    const int gi = blockIdx.x, path = blockIdx.y, b = gi >> 11, tid = threadIdx.x;
    short* aug = aug0 + (size_t)path * MT * KAUG;
    const float* c1 = C10 + (size_t)path * BB * DD * RS + (long)b * DD * RS;
    const short* qrow = aug + (long)gi * KAUG;
    float acc[RS];
#pragma unroll
    for (int r = 0; r < RS; ++r) acc[r] = 0.f;
#pragma unroll
    for (int c = 0; c < 4; ++c) {
        int d = tid + 256 * c;
        float q = bf2f(qrow[d]);
        const float* cr = c1 + (long)d * RS;
#pragma unroll
        for (int r = 0; r < RS; ++r) acc[r] = fmaf(q, cr[r], acc[r]);
    }
#pragma unroll
    for (int r = 0; r < RS; ++r)
#pragma unroll
        for (int off = 32; off; off >>= 1) acc[r] += __shfl_down(acc[r], off, 64);
    __shared__ float red[4][RS];
    if ((tid & 63) == 0)
#pragma unroll
        for (int r = 0; r < RS; ++r) red[tid >> 6][r] = acc[r];
    __syncthreads();
    if (tid < RS)
        aug[(long)gi * KAUG + 1024 + tid] =
            f2bf(red[0][tid] + red[1][tid] + red[2][tid] + red[3][tid]);
}

// ---------------------------------------------------------------------------
// vdT[b][d][t] = bf16(vb[b][t][d] * d2[b*TT+t])   (vb bf16)
// ---------------------------------------------------------------------------
__global__ __launch_bounds__(256)
void vdt_kernel(const short* __restrict__ v, const float* __restrict__ d2,
                short* __restrict__ o)
{
    const int t0 = blockIdx.x * 32, d0 = blockIdx.y * 32, b = blockIdx.z;
    const int tx = threadIdx.x & 31, ty = threadIdx.x >> 5;
    __shared__ float tile[32][33];
    for (int s = 0; s < 32; s += 8) {
        int t = t0 + ty + s;
        tile[ty + s][tx] = bf2f(v[((long)b * TT + t) * DD + d0 + tx]) * d2[(long)b * TT + t];
    }
    __syncthreads();
    for (int s = 0; s < 32; s += 8) {
        int d = d0 + ty + s;
        o[((long)b * DD + d) * TT + t0 + tx] = f2bf(tile[tx][ty + s]);
    }
}

// ---------------------------------------------------------------------------
extern "C" void kernel_launch(void* const* d_in, const int* in_sizes, int n_in,
                              void* d_out, int out_size, void* d_ws, size_t ws_size,
                              hipStream_t stream)
{
    (void)in_sizes; (void)n_in; (void)out_size; (void)ws_size;
    const float* x = (const float*)d_in[0];
    const float* W[27];
    for (int i = 1; i < 27; ++i) W[i] = (const float*)d_in[i];
    float* out = (float*)d_out;

    char* ws = (char*)d_ws;
    size_t off = 0;
    auto alloc = [&](size_t bytes) -> void* {
        void* p = ws + off; off += (bytes + 255) & ~(size_t)255; return p;
    };
    short* xb     = (short*)alloc((size_t)MT * DD * 2);          // -> VDT
    short* WcatT  = (short*)alloc((size_t)GLD * DD * 2);
    short* W2catT = (short*)alloc((size_t)8 * DD * 64 * 2);
    short* Gb512  = (short*)alloc((size_t)MT * 512 * 2);
    short* Wob    = (short*)alloc((size_t)DD * DD * 2);
    short* S1b    = (short*)alloc((size_t)MT * DD * 2);          // mvo bf16
    short* VB     = (short*)alloc((size_t)MT * DD * 2);          // v bf16
    short* QGaug  = (short*)alloc((size_t)MT * KAUG * 2);        // | contiguous
    short* QSGaug = (short*)alloc((size_t)MT * KAUG * 2);        // |
    short* KBaug  = (short*)alloc((size_t)MT * KAUG * 2);
    short* KSBaug = (short*)alloc((size_t)MT * KAUG * 2);
    short* CM     = (short*)alloc((size_t)MT * DD * 2);
    short* P      = (short*)alloc((size_t)BB * TT * TT * 2);
    float* d1   = (float*)alloc((size_t)MT * 4);
    float* d1s  = (float*)alloc((size_t)MT * 4);
    float* d2   = (float*)alloc((size_t)MT * 4);
    float* B1T  = (float*)alloc((size_t)RS * MT * 4);            // | contiguous
    float* B1sT = (float*)alloc((size_t)RS * MT * 4);            // | (e_kernel
    float* A2T  = (float*)alloc((size_t)RS * MT * 4);            // |  indexes)
    short* B2T  = (short*)alloc((size_t)RS * MT * 2);
    float* C1   = (float*)alloc((size_t)BB * DD * RS * 4);       // | contiguous
    float* C1s  = (float*)alloc((size_t)BB * DD * RS * 4);       // | (zb paths)
    float* A2tV = (float*)alloc((size_t)BB * RS * DD * 4);
    float* rowsum = (float*)alloc((size_t)MT * 4);               // | zero block
    float* E    = (float*)alloc((size_t)3 * BB * 64 * RS * 4);   // |
    float* hB   = (float*)alloc((size_t)MT * RS * 4);

    short* VDT = xb;        // xb dead after stage-1
    short* cm  = CM;

    const long n4 = (long)MT * DD / 4;
    const int ZN = MT + 3 * BB * 64 * RS;   // rowsum + E floats (contiguous)

    // --- input/weight conversion (+ zero accumulators) ---
    f2bf_vec_kernel<<<n4 / 256, 256, 0, stream>>>(x, xb, n4);
    ConcatArgs ca;
    {
        const int w1idx[8] = {1, 3, 5, 7, 9, 11, 13, 15};
        for (int s = 0; s < 8; ++s) { ca.p[s] = W[w1idx[s]]; ca.col0[s] = s * 64; ca.wid[s] = 64; }
        const int didx[9] = {18, 19, 20, 21, 22, 23, 24, 25, 26};
        const int dcol[9] = {512, 513, 529, 545, 546, 562, 578, 579, 595};
        const int dwid[9] = {1, 16, 16, 1, 16, 16, 1, 16, 16};
        for (int s = 0; s < 9; ++s) { ca.p[8 + s] = W[didx[s]]; ca.col0[8 + s] = dcol[s]; ca.wid[8 + s] = dwid[s]; }
    }
    concat_w1_kernel<<<GLD, 256, 0, stream>>>(ca, WcatT, rowsum, ZN);
    Ptrs8 p8;
    {
        const int w2idx[8] = {2, 4, 6, 8, 10, 12, 14, 16};
        for (int s = 0; s < 8; ++s) p8.p[s] = W[w2idx[s]];
    }
    concat_w2_kernel<<<dim3(DD / 64, 8), 256, 0, stream>>>(p8, W2catT);
    f2bf_vec_kernel<<<((long)DD * DD / 4) / 256, 256, 0, stream>>>(W[17], Wob, (long)DD * DD / 4);

    // --- stage-1 (SoA scatter epilogue; G never materialized) ---
    gemm_s1<<<dim3(GLD / 128, MT / 128, 1), 512, 0, stream>>>(
        xb, WcatT, Gb512, d1, d1s, d2, B1T, B1sT, A2T, B2T,
        QGaug, QSGaug, KBaug, KSBaug);

    // --- factored skinny reductions: E then C1/C1s/A2tV ---
    e_kernel<<<dim3(16, BB, 3), 256, 0, stream>>>(Gb512, B1T, E);
    c1w_kernel<<<dim3(DD / 64, 3, BB), 256, 0, stream>>>(W2catT, E, C1, A2tV);

    // --- stage-2: one launch, 6 slices ---
    S2A a;
    a.sl[0] = {0, 0, 1, QGaug,  nullptr};   // q*mg
    a.sl[1] = {0, 3, 4, QSGaug, nullptr};   // qs*mgs
    a.sl[2] = {1, 2, 0, KBaug,  d1};        // k*d1 -> aug
    a.sl[3] = {1, 5, 0, KSBaug, d1s};       // ks*d1s -> aug
    a.sl[4] = {3, 6, 0, VB,     nullptr};   // v bf16
    a.sl[5] = {3, 7, 0, S1b,    nullptr};   // mvo bf16
    stage2_kernel<<<dim3(DD / 128, MT / 128, 6), 512, 0, stream>>>(Gb512, W2catT, a);

    // --- vdT from bf16 v ---
    vdt_kernel<<<dim3(TT / 32, DD / 32, BB), 256, 0, stream>>>(VB, d2, VDT);

    // --- zB into aug cols (both paths) ---
    zb_kernel<<<dim3(MT, 2), 256, 0, stream>>>(QGaug, C1);

    // --- fused hm/hs GEMMs + HyperGLU -> P, rowsum (4-wave BK=64 core) ---
    hmhs_kernel<<<dim3(TT / 128, TT / 128, BB), 256, 0, stream>>>(
        QGaug, QSGaug, KBaug, KSBaug, P, rowsum);

    // --- finish: hB (inv folded) ---
    finish_kernel<<<dim3(TT, BB), 256, 0, stream>>>(P, B2T, rowsum, hB);

    // --- context + inv + rank16 + mvo -> cm ---
    ctx_kernel<<<dim3(DD / 128, TT / 128, BB), 512, 0, stream>>>(
        P, VDT, S1b, hB, A2tV, rowsum, cm);

    // --- out = cm @ Wo^T ---
    gemm_nt<0><<<dim3(DD / 128, MT / 128, 1), 512, 0, stream>>>(
        cm, Wob, out, DD, DD, DD, DD, 0, 0, 0);
}

// Round 18
// 250.006 us; speedup vs baseline: 1.4090x; 1.0429x over previous
//
#include <hip/hip_runtime.h>
#include <math.h>

#define BB 2
#define TT 2048
#define DD 1024
#define RS 16
#define MT (BB*TT)      // 4096 flattened rows
#define GLD 640         // stage-1 concat output width (611 used, padded)
#define KAUG 1088       // 1024 + 16 (zB/A1) + 48 zero pad; multiple of 64

typedef __attribute__((ext_vector_type(8))) short s16x8;
typedef __attribute__((ext_vector_type(4))) float f32x4;

__device__ __forceinline__ short f2bf(float f) {
    union { float f; unsigned u; } v; v.f = f;
    unsigned r = (v.u + 0x7fffu + ((v.u >> 16) & 1u)) >> 16;
    return (short)r;
}
__device__ __forceinline__ float bf2f(short s) {
    union { unsigned u; float f; } v; v.u = ((unsigned)(unsigned short)s) << 16;
    return v.f;
}

__device__ __forceinline__ void gload16(const void* g, void* l) {
    __builtin_amdgcn_global_load_lds((const __attribute__((address_space(1))) void*)g,
                                     (__attribute__((address_space(3))) void*)l, 16, 0, 0);
}

// XCD-aware block swizzle (all grids are multiples of 8 -> bijective).
__device__ __forceinline__ void xcd_swz(int& bx, int& by, int& bz)
{
    const int gx = gridDim.x, gy = gridDim.y;
    const int n = gx * gy * (int)gridDim.z;
    int flat = (bz * gy + by) * gx + bx;
    const int cpx = n >> 3;
    flat = (flat & 7) * cpx + (flat >> 3);
    bx = flat % gx; by = (flat / gx) % gy; bz = flat / (gx * gy);
}

// ---------------------------------------------------------------------------
// 8-wave (512-thr) pipelined 128x128 NT core (BK=32), 2M x 4N wave layout.
// Kept for stage2 only (K=64 = 2 tiles at BK=32; BK=64 would kill the
// double buffer there). acc[4][2] = 32 VGPR. Counted vmcnt; raw s_barrier.
// ---------------------------------------------------------------------------
template<int DEPTH>
__device__ __forceinline__ void gemm_core128p(const short* __restrict__ A,
                                              const short* __restrict__ Bt,
                                              int K, int lda, int ldb,
                                              int bi, int bj, short* smem,
                                              f32x4 (&acc)[4][2])
{
    const int tid = threadIdx.x;
    const int wv = tid >> 6, lane = tid & 63;
    const int wr = (wv >> 2) * 64, wc = (wv & 3) * 32;

#pragma unroll
    for (int m = 0; m < 4; ++m)
#pragma unroll
        for (int n = 0; n < 2; ++n) acc[m][n] = (f32x4){0.f, 0.f, 0.f, 0.f};

    const int srow = wv * 16 + (lane >> 2);                // staging row 0..127
    const int sg   = ((lane & 3) ^ ((srow >> 1) & 3)) * 8; // swizzled src granule
    const int frow = lane & 15;
    const int gidx = lane >> 4;
    const int koff = (gidx ^ ((frow >> 1) & 3)) * 8;       // swizzled read offset

    const int nt = K >> 5;
    const long arow = (long)(bi + srow) * lda + sg;
    const long brow = (long)(bj + srow) * ldb + sg;

    auto stage = [&](int t, int q) {
        short* As = smem + q * 8192;
        short* Bs = As + 4096;
        const int k0 = t << 5;
        gload16(A + arow + k0, As + wv*512);
        gload16(Bt + brow + k0, Bs + wv*512);
    };

    stage(0, 0);
    if (nt > 1) stage(1, 1);
    if (DEPTH == 3) { if (nt > 2) stage(2, 2); }

    int q = 0;
    for (int t = 0; t < nt; ++t) {
        const int rem = nt - 1 - t;
        if (DEPTH == 3 && rem >= 2) asm volatile("s_waitcnt vmcnt(4)" ::: "memory");
        else if (rem >= 1)          asm volatile("s_waitcnt vmcnt(2)" ::: "memory");
        else                        asm volatile("s_waitcnt vmcnt(0)" ::: "memory");
        __builtin_amdgcn_s_barrier();          // all waves' tile-t data visible

        const short* As = smem + q * 8192;
        const short* Bs = As + 4096;
        s16x8 af[4], bfr[2];
#pragma unroll
        for (int m = 0; m < 4; ++m)
            af[m] = *(const s16x8*)&As[(wr + m*16 + frow) * 32 + koff];
#pragma unroll
        for (int n = 0; n < 2; ++n)
            bfr[n] = *(const s16x8*)&Bs[(wc + n*16 + frow) * 32 + koff];
        asm volatile("s_waitcnt lgkmcnt(0)" ::: "memory");  // reads in registers
        __builtin_amdgcn_sched_barrier(0);                  // rule-18 fence
        __builtin_amdgcn_s_barrier();          // all waves done READING buf q

        if (t + DEPTH < nt) stage(t + DEPTH, q);  // overwrite safe; overlaps MFMA

#pragma unroll
        for (int m = 0; m < 4; ++m)
#pragma unroll
            for (int n = 0; n < 2; ++n)
                acc[m][n] = __builtin_amdgcn_mfma_f32_16x16x32_bf16(af[m], bfr[n], acc[m][n], 0, 0, 0);
        q = (q == DEPTH - 1) ? 0 : q + 1;
    }
}

// ---------------------------------------------------------------------------
// 8-wave (512-thr) BK=64 depth-2 core, 2M x 4N layout, acc[4][2].
// r17 validated the BK=64 mechanism on hmhs (58.6->51.7us, MfmaUtil 29%):
// grid-limited kernels (ctx/Wo/s1 at 1-2 blocks/CU) have free LDS, so 64KB
// double-buffered tiles halve the barrier count with no occupancy loss.
// Swizzle: 8 granules/row; phys = glog ^ (row&7); inverse on global source;
// 2-way read conflict = free (m136). 4 loads/lane/tile -> steady vmcnt(4).
// Two k-sub-steps cap fragment liveness; buffer-release barrier after LAST
// read. K must be a multiple of 64.
// ---------------------------------------------------------------------------
__device__ __forceinline__ void gemm_core128p8_bk64(const short* __restrict__ A,
                                                    const short* __restrict__ Bt,
                                                    int K, int lda, int ldb,
                                                    int bi, int bj, short* smem,
                                                    f32x4 (&acc)[4][2])
{
    const int tid = threadIdx.x;
    const int wv = tid >> 6, lane = tid & 63;
    const int wr = (wv >> 2) * 64, wc = (wv & 3) * 32;

#pragma unroll
    for (int m = 0; m < 4; ++m)
#pragma unroll
        for (int n = 0; n < 2; ++n) acc[m][n] = (f32x4){0.f, 0.f, 0.f, 0.f};

    const int rloc  = lane >> 3;          // 0..7 row within the wave's 8-row group
    const int gphys = lane & 7;           // physical granule this lane writes
    const int frow  = lane & 15;
    const int gsub  = lane >> 4;          // 0..3 logical sub-granule (ks=0)

    const int nt = K >> 6;                // 64-wide K tiles

    // stage tile t into buffer q: 2 A-loads + 2 B-loads per lane
    auto stage = [&](int t, int q) {
        short* As = smem + q * 16384;     // 32KB buffer: A 8192 sh + B 8192 sh
        short* Bs = As + 8192;
        const int k0 = t << 6;
#pragma unroll
        for (int p = 0; p < 2; ++p) {
            const int row = p*64 + wv*8 + rloc;
            const int src = ((gphys ^ (row & 7)) * 8);   // inverse swizzle
            gload16(A  + (long)(bi + row) * lda + k0 + src, As + (p*64 + wv*8) * 64);
            gload16(Bt + (long)(bj + row) * ldb + k0 + src, Bs + (p*64 + wv*8) * 64);
        }
    };

    stage(0, 0);
    if (nt > 1) stage(1, 1);

    int q = 0;
    for (int t = 0; t < nt; ++t) {
        if (t + 1 < nt) asm volatile("s_waitcnt vmcnt(4)" ::: "memory");
        else            asm volatile("s_waitcnt vmcnt(0)" ::: "memory");
        __builtin_amdgcn_s_barrier();          // tile-t data visible

        const short* As = smem + q * 16384;
        const short* Bs = As + 8192;

        // ---- k-sub-step 0 (cols 0..31) ----
        {
            s16x8 af[4], bfr[2];
#pragma unroll
            for (int m = 0; m < 4; ++m) {
                const int row = wr + m*16 + frow;
                af[m] = *(const s16x8*)&As[row*64 + ((gsub ^ (row & 7)) * 8)];
            }
#pragma unroll
            for (int n = 0; n < 2; ++n) {
                const int row = wc + n*16 + frow;
                bfr[n] = *(const s16x8*)&Bs[row*64 + ((gsub ^ (row & 7)) * 8)];
            }
            asm volatile("s_waitcnt lgkmcnt(0)" ::: "memory");
            __builtin_amdgcn_sched_barrier(0);
#pragma unroll
            for (int m = 0; m < 4; ++m)
#pragma unroll
                for (int n = 0; n < 2; ++n)
                    acc[m][n] = __builtin_amdgcn_mfma_f32_16x16x32_bf16(af[m], bfr[n], acc[m][n], 0, 0, 0);
        }
        // ---- k-sub-step 1 (cols 32..63) ----
        {
            s16x8 af[4], bfr[2];
#pragma unroll
            for (int m = 0; m < 4; ++m) {
                const int row = wr + m*16 + frow;
                af[m] = *(const s16x8*)&As[row*64 + (((gsub + 4) ^ (row & 7)) * 8)];
            }
#pragma unroll
            for (int n = 0; n < 2; ++n) {
                const int row = wc + n*16 + frow;
                bfr[n] = *(const s16x8*)&Bs[row*64 + (((gsub + 4) ^ (row & 7)) * 8)];
            }
            asm volatile("s_waitcnt lgkmcnt(0)" ::: "memory");
            __builtin_amdgcn_sched_barrier(0);
            __builtin_amdgcn_s_barrier();      // all waves done READING buf q

            if (t + 2 < nt) stage(t + 2, q);   // overwrite safe; overlaps MFMA

#pragma unroll
            for (int m = 0; m < 4; ++m)
#pragma unroll
                for (int n = 0; n < 2; ++n)
                    acc[m][n] = __builtin_amdgcn_mfma_f32_16x16x32_bf16(af[m], bfr[n], acc[m][n], 0, 0, 0);
        }
        q ^= 1;
    }
}

// ---------------------------------------------------------------------------
// 4-wave (256-thr) BK=64 depth-2 core, 2x2 wave layout, acc[4][4].
// r17-proven for hmhs (51.7us, MfmaUtil 29%). Used by hmhs ONLY
// (r13: 8-wave hmhs thrashed L2; r15: no rank-16 atomics in epilogue).
// ---------------------------------------------------------------------------
__device__ __forceinline__ void gemm_core128_bk64(const short* __restrict__ A,
                                                  const short* __restrict__ Bt,
                                                  int K, int lda, int ldb,
                                                  int bi, int bj, short* smem,
                                                  f32x4 (&acc)[4][4])
{
    const int tid = threadIdx.x;
    const int wv = tid >> 6, lane = tid & 63;
    const int wr = (wv >> 1) * 64, wc = (wv & 1) * 64;

#pragma unroll
    for (int m = 0; m < 4; ++m)
#pragma unroll
        for (int n = 0; n < 4; ++n) acc[m][n] = (f32x4){0.f, 0.f, 0.f, 0.f};

    const int rloc  = lane >> 3;          // 0..7 row within an 8-row group
    const int gphys = lane & 7;           // physical granule this lane writes
    const int frow  = lane & 15;
    const int gsub  = lane >> 4;          // 0..3 logical sub-granule (ks=0)

    const int nt = K >> 6;                // 64-wide K tiles

    auto stage = [&](int t, int q) {
        short* As = smem + q * 16384;     // 32KB buffer: A 8192 sh + B 8192 sh
        short* Bs = As + 8192;
        const int k0 = t << 6;
#pragma unroll
        for (int p = 0; p < 4; ++p) {
            const int row = p*32 + wv*8 + rloc;
            const int src = ((gphys ^ (row & 7)) * 8);   // inverse swizzle
            gload16(A  + (long)(bi + row) * lda + k0 + src, As + (p*32 + wv*8) * 64);
            gload16(Bt + (long)(bj + row) * ldb + k0 + src, Bs + (p*32 + wv*8) * 64);
        }
    };

    stage(0, 0);
    if (nt > 1) stage(1, 1);

    int q = 0;
    for (int t = 0; t < nt; ++t) {
        if (t + 1 < nt) asm volatile("s_waitcnt vmcnt(8)" ::: "memory");
        else            asm volatile("s_waitcnt vmcnt(0)" ::: "memory");
        __builtin_amdgcn_s_barrier();          // tile-t data visible

        const short* As = smem + q * 16384;
        const short* Bs = As + 8192;

        // ---- k-sub-step 0 (cols 0..31 of the tile) ----
        {
            s16x8 af[4], bfr[4];
#pragma unroll
            for (int m = 0; m < 4; ++m) {
                const int row = wr + m*16 + frow;
                af[m] = *(const s16x8*)&As[row*64 + ((gsub ^ (row & 7)) * 8)];
            }
#pragma unroll
            for (int n = 0; n < 4; ++n) {
                const int row = wc + n*16 + frow;
                bfr[n] = *(const s16x8*)&Bs[row*64 + ((gsub ^ (row & 7)) * 8)];
            }
            asm volatile("s_waitcnt lgkmcnt(0)" ::: "memory");
            __builtin_amdgcn_sched_barrier(0);
#pragma unroll
            for (int m = 0; m < 4; ++m)
#pragma unroll
                for (int n = 0; n < 4; ++n)
                    acc[m][n] = __builtin_amdgcn_mfma_f32_16x16x32_bf16(af[m], bfr[n], acc[m][n], 0, 0, 0);
        }
        // ---- k-sub-step 1 (cols 32..63) ----
        {
            s16x8 af[4], bfr[4];
#pragma unroll
            for (int m = 0; m < 4; ++m) {
                const int row = wr + m*16 + frow;
                af[m] = *(const s16x8*)&As[row*64 + (((gsub + 4) ^ (row & 7)) * 8)];
            }
#pragma unroll
            for (int n = 0; n < 4; ++n) {
                const int row = wc + n*16 + frow;
                bfr[n] = *(const s16x8*)&Bs[row*64 + (((gsub + 4) ^ (row & 7)) * 8)];
            }
            asm volatile("s_waitcnt lgkmcnt(0)" ::: "memory");
            __builtin_amdgcn_sched_barrier(0);
            __builtin_amdgcn_s_barrier();      // all waves done READING buf q

            if (t + 2 < nt) stage(t + 2, q);   // overwrite safe; overlaps MFMA

#pragma unroll
            for (int m = 0; m < 4; ++m)
#pragma unroll
                for (int n = 0; n < 4; ++n)
                    acc[m][n] = __builtin_amdgcn_mfma_f32_16x16x32_bf16(af[m], bfr[n], acc[m][n], 0, 0, 0);
        }
        q ^= 1;
    }
}

// Generic batched NT GEMM (BK=64 core); STORE 0 = fp32 out, 1 = bf16 out.
template<int STORE>
__global__ __launch_bounds__(512)
void gemm_nt(const short* __restrict__ A, const short* __restrict__ Bt,
             void* __restrict__ Cv, int K, int lda, int ldb, int ldc,
             long sA, long sB, long sC)
{
    int bx = blockIdx.x, by = blockIdx.y, bz = blockIdx.z;
    xcd_swz(bx, by, bz);
    const short* Ab = A  + (long)bz * sA;
    const short* Bb = Bt + (long)bz * sB;
    const int bi = by * 128, bj = bx * 128;
    __shared__ __align__(16) short smem[32768];
    f32x4 acc[4][2];
    gemm_core128p8_bk64(Ab, Bb, K, lda, ldb, bi, bj, smem, acc);

    const int lane = threadIdx.x & 63, wv = threadIdx.x >> 6;
    const int wr = (wv >> 2) * 64, wc = (wv & 3) * 32;
    const int col0 = lane & 15, row0 = (lane >> 4) * 4;
#pragma unroll
    for (int m = 0; m < 4; ++m)
#pragma unroll
        for (int n = 0; n < 2; ++n)
#pragma unroll
            for (int r = 0; r < 4; ++r) {
                int i = bi + wr + m*16 + row0 + r;
                int j = bj + wc + n*16 + col0;
                if (STORE == 0)
                    ((float*)Cv + (long)bz * sC)[(long)i * ldc + j] = acc[m][n][r];
                else
                    ((short*)Cv + (long)bz * sC)[(long)i * ldc + j] = f2bf(acc[m][n][r]);
            }
}

// ---------------------------------------------------------------------------
// Stage-1: xb @ WcatT^T (BK=64 core). Epilogue: cols <512 -> Gb512 bf16;
// cols 512..610 scattered directly to SoA generator arrays (G never stored).
// Also zeroes aug pad cols 1040..1087 (at j==512, once per row).
// ---------------------------------------------------------------------------
__global__ __launch_bounds__(512)
void gemm_s1(const short* __restrict__ xb, const short* __restrict__ WcatT,
             short* __restrict__ Gb512,
             float* __restrict__ d1, float* __restrict__ d1s, float* __restrict__ d2,
             float* __restrict__ B1T, float* __restrict__ B1sT, float* __restrict__ A2T,
             short* __restrict__ B2T,
             short* __restrict__ QGaug, short* __restrict__ QSGaug,
             short* __restrict__ KBaug, short* __restrict__ KSBaug)
{
    int bx = blockIdx.x, by = blockIdx.y, bz = blockIdx.z;
    xcd_swz(bx, by, bz);
    const int bi = by * 128, bj = bx * 128;
    __shared__ __align__(16) short smem[32768];
    f32x4 acc[4][2];
    gemm_core128p8_bk64(xb, WcatT, DD, DD, DD, bi, bj, smem, acc);

    const int lane = threadIdx.x & 63, wv = threadIdx.x >> 6;
    const int wr = (wv >> 2) * 64, wc = (wv & 3) * 32;
    const int col0 = lane & 15, row0 = (lane >> 4) * 4;
#pragma unroll
    for (int m = 0; m < 4; ++m)
#pragma unroll
        for (int n = 0; n < 2; ++n)
#pragma unroll
            for (int r = 0; r < 4; ++r) {
                int i = bi + wr + m*16 + row0 + r;
                int j = bj + wc + n*16 + col0;
                float val = acc[m][n][r];
                if (j < 512) {
                    Gb512[(long)i * 512 + j] = f2bf(val);
                } else if (j == 512) {
                    d1[i] = val;
                    for (int q = 0; q < KAUG - 1040; ++q) {
                        QGaug [(long)i * KAUG + 1040 + q] = 0;
                        QSGaug[(long)i * KAUG + 1040 + q] = 0;
                        KBaug [(long)i * KAUG + 1040 + q] = 0;
                        KSBaug[(long)i * KAUG + 1040 + q] = 0;
                    }
                } else if (j < 529) {
                    KBaug[(long)i * KAUG + 1024 + (j - 513)] = f2bf(val);
                } else if (j < 545) {
                    B1T[(long)(j - 529) * MT + i] = val;
                } else if (j == 545) {
                    d1s[i] = val;
                } else if (j < 562) {
                    KSBaug[(long)i * KAUG + 1024 + (j - 546)] = f2bf(val);
                } else if (j < 578) {
                    B1sT[(long)(j - 562) * MT + i] = val;
                } else if (j == 578) {
                    d2[i] = val;
                } else if (j < 595) {
                    A2T[(long)(j - 579) * MT + i] = val;
                } else if (j < 611) {
                    B2T[(long)(j - 595) * MT + i] = f2bf(val);
                }
            }
}

// ---------------------------------------------------------------------------
// E[kind][b][c][r] = sum_t Gb512[b*TT+t][col0(kind)+c] * BT_kind[r][b*TT+t]
// ---------------------------------------------------------------------------
__global__ __launch_bounds__(256)
void e_kernel(const short* __restrict__ Gb512, const float* __restrict__ BT0,
              float* __restrict__ E)
{
    const int tc = blockIdx.x, b = blockIdx.y, kind = blockIdx.z;
    const int col0 = (kind == 0) ? 128 : (kind == 1) ? 320 : 384;
    const float* BT = BT0 + (size_t)kind * RS * MT;
    const int c = threadIdx.x & 63, rg = threadIdx.x >> 6;
    float acc[4] = {0.f, 0.f, 0.f, 0.f};
    const int t0 = tc * (TT / 16);
#pragma unroll 2
    for (int tt = 0; tt < TT / 16; ++tt) {
        const long gi = (long)b * TT + t0 + tt;
        float g = bf2f(Gb512[gi * 512 + col0 + c]);
#pragma unroll
        for (int q = 0; q < 4; ++q)
            acc[q] = fmaf(g, BT[(long)(rg * 4 + q) * MT + gi], acc[q]);
    }
#pragma unroll
    for (int q = 0; q < 4; ++q)
        atomicAdd(&E[(((long)kind * BB + b) * 64 + c) * RS + rg * 4 + q], acc[q]);
}

// ---------------------------------------------------------------------------
// c1w: C1[kind][b][d][r] = sum_c W2T[s(kind)][d][c] * E[kind][b][c][r]
// kind 2 writes A2tV[b][r][d] layout instead.
// ---------------------------------------------------------------------------
__global__ __launch_bounds__(256)
void c1w_kernel(const short* __restrict__ W2, const float* __restrict__ E,
                float* __restrict__ C1, float* __restrict__ A2tV)
{
    const int d0 = blockIdx.x * 64, kind = blockIdx.y, b = blockIdx.z;
    const int s = (kind == 0) ? 2 : (kind == 1) ? 5 : 6;
    __shared__ float El[64][RS];
    {
        const float* Eb = E + ((long)kind * BB + b) * 64 * RS;
        int q = threadIdx.x;
#pragma unroll
        for (int k = 0; k < 4; ++k) ((float*)El)[q + 256 * k] = Eb[q + 256 * k];
    }
    __syncthreads();
    const int dl = threadIdx.x & 63, rg = threadIdx.x >> 6;
    const int d = d0 + dl;
    const short* wrow = W2 + ((long)s * DD + d) * 64;
    float acc[4] = {0.f, 0.f, 0.f, 0.f};
#pragma unroll
    for (int c8 = 0; c8 < 8; ++c8) {
        s16x8 wv = *(const s16x8*)&wrow[c8 * 8];
#pragma unroll
        for (int u = 0; u < 8; ++u) {
            float w = bf2f(wv[u]);
#pragma unroll
            for (int q = 0; q < 4; ++q)
                acc[q] = fmaf(w, El[c8 * 8 + u][rg * 4 + q], acc[q]);
        }
    }
    if (kind < 2) {
        float* dst = C1 + (size_t)kind * BB * DD * RS;
#pragma unroll
        for (int q = 0; q < 4; ++q)
            dst[((long)b * DD + d) * RS + rg * 4 + q] = acc[q];
    } else {
#pragma unroll
        for (int q = 0; q < 4; ++q)
            A2tV[((long)b * RS + rg * 4 + q) * DD + d] = acc[q];
    }
}

// ---------------------------------------------------------------------------
// hmhs_fused: two sequential 4-wave BK=64 depth-2 core passes (gate, scale),
// 64 KB LDS, 256 threads (r17-proven: 51.7us). Epilogue:
// P = fast_softplus(hs) * relu(hm) (bf16, norm deferred), rowsum += hm^2.
// ---------------------------------------------------------------------------
__global__ __launch_bounds__(256)
void hmhs_kernel(const short* __restrict__ QGaug, const short* __restrict__ QSGaug,
                 const short* __restrict__ KBaug, const short* __restrict__ KSBaug,
                 short* __restrict__ P, float* __restrict__ rowsum)
{
    int bx = blockIdx.x, by = blockIdx.y, bz = blockIdx.z;
    xcd_swz(bx, by, bz);
    const int b = bz;
    const int bi = by * 128, bj = bx * 128;
    __shared__ __align__(16) short smem[32768];   // 64 KB: 2 x (16KB A + 16KB B)
    f32x4 acc[4][4], acc2[4][4];
    gemm_core128_bk64(QGaug  + (long)b * TT * KAUG, KBaug  + (long)b * TT * KAUG,
                      KAUG, KAUG, KAUG, bi, bj, smem, acc);
    gemm_core128_bk64(QSGaug + (long)b * TT * KAUG, KSBaug + (long)b * TT * KAUG,
                      KAUG, KAUG, KAUG, bi, bj, smem, acc2);

    const int lane = threadIdx.x & 63, wv = threadIdx.x >> 6;
    const int wr = (wv >> 1) * 64, wc = (wv & 1) * 64;
    const int col0 = lane & 15, row0 = (lane >> 4) * 4;
    short* Pb = P + (long)b * TT * TT;

    float ss[4][4];
#pragma unroll
    for (int m = 0; m < 4; ++m)
#pragma unroll
        for (int r = 0; r < 4; ++r) ss[m][r] = 0.f;

#pragma unroll
    for (int m = 0; m < 4; ++m)
#pragma unroll
        for (int n = 0; n < 4; ++n)
#pragma unroll
            for (int r = 0; r < 4; ++r) {
                int i = bi + wr + m*16 + row0 + r;
                int j = bj + wc + n*16 + col0;
                float hmv = acc[m][n][r];
                float sv  = acc2[m][n][r];
                // fast softplus: 2 HW transcendentals (error << bf16 rounding)
                float sp  = fmaxf(sv, 0.f) + __logf(1.f + __expf(-fabsf(sv)));
                Pb[(long)i * TT + j] = f2bf(sp * fmaxf(hmv, 0.f));
                ss[m][r] = fmaf(hmv, hmv, ss[m][r]);
            }

#pragma unroll
    for (int m = 0; m < 4; ++m)
#pragma unroll
        for (int r = 0; r < 4; ++r) {
            float v = ss[m][r];
            v += __shfl_xor(v, 1, 64);
            v += __shfl_xor(v, 2, 64);
            v += __shfl_xor(v, 4, 64);
            v += __shfl_xor(v, 8, 64);
            if (col0 == 0)
                atomicAdd(&rowsum[(long)b * TT + bi + wr + m*16 + row0 + r], v);
        }
}

// ---------------------------------------------------------------------------
// finish: hB[i][r] = inv[i] * sum_j P[i][j] * B2T[r][j]
// ---------------------------------------------------------------------------
__global__ __launch_bounds__(256)
void finish_kernel(const short* __restrict__ P, const short* __restrict__ B2T,
                   const float* __restrict__ rowsum, float* __restrict__ hB)
{
    const int i = blockIdx.x, b = blockIdx.y, tid = threadIdx.x;
    const long gi = (long)b * TT + i;
    const float inv = 1.f / (sqrtf(rowsum[gi]) + 1e-8f);
    const short* Pr = P + ((long)b * TT + i) * TT;
    const long tb = (long)b * TT;
    const int j0 = tid * 8;

    float hb[RS];
#pragma unroll
    for (int r = 0; r < RS; ++r) hb[r] = 0.f;

    s16x8 pv = *(const s16x8*)&Pr[j0];
    float pf[8];
#pragma unroll
    for (int q = 0; q < 8; ++q) pf[q] = bf2f(pv[q]);
#pragma unroll
    for (int r = 0; r < RS; ++r) {
        s16x8 bv = *(const s16x8*)&B2T[(long)r * MT + tb + j0];
#pragma unroll
        for (int q = 0; q < 8; ++q) hb[r] = fmaf(pf[q], bf2f(bv[q]), hb[r]);
    }
#pragma unroll
    for (int r = 0; r < RS; ++r)
#pragma unroll
        for (int off = 32; off; off >>= 1) hb[r] += __shfl_down(hb[r], off, 64);
    __shared__ float red[4][RS];
    if ((tid & 63) == 0)
#pragma unroll
        for (int r = 0; r < RS; ++r) red[tid >> 6][r] = hb[r];
    __syncthreads();
    if (tid < RS)
        hB[gi * RS + tid] = (red[0][tid] + red[1][tid] + red[2][tid] + red[3][tid]) * inv;
}

// ---------------------------------------------------------------------------
// Stage-2 multi-slice GEMM (K=64 per pass, BK=32 core).
// mode 0 (GATE):   two passes (sa,sb); out bf16(acc*acc2) at ldc KAUG.
// mode 1 (SCALED): outS bf16(acc*rs[i]) at ldc KAUG.
// mode 3 (BF16):   outS bf16 ldc DD.
// ---------------------------------------------------------------------------
struct S2S { int mode, sa, sb; short* outS; const float* rs; };
struct S2A { S2S sl[6]; };

__global__ __launch_bounds__(512)
void stage2_kernel(const short* __restrict__ Gb, const short* __restrict__ W2,
                   S2A args)
{
    int bx = blockIdx.x, by = blockIdx.y, bz = blockIdx.z;
    xcd_swz(bx, by, bz);
    const S2S sl = args.sl[bz];
    const int bi = by * 128, bj = bx * 128;
    __shared__ __align__(16) short smem[16384];
    f32x4 acc[4][2];
    gemm_core128p<2>(Gb + sl.sa * 64, W2 + (long)sl.sa * DD * 64, 64, 512, 64, bi, bj, smem, acc);
    f32x4 acc2[4][2];
    if (sl.mode == 0)
        gemm_core128p<2>(Gb + sl.sb * 64, W2 + (long)sl.sb * DD * 64, 64, 512, 64, bi, bj, smem, acc2);

    const int lane = threadIdx.x & 63, wv = threadIdx.x >> 6;
    const int wr = (wv >> 2) * 64, wc = (wv & 3) * 32;
    const int col0 = lane & 15, row0 = (lane >> 4) * 4;
#pragma unroll
    for (int m = 0; m < 4; ++m)
#pragma unroll
        for (int n = 0; n < 2; ++n)
#pragma unroll
            for (int r = 0; r < 4; ++r) {
                int i = bi + wr + m*16 + row0 + r;
                int j = bj + wc + n*16 + col0;
                float val = acc[m][n][r];
                if (sl.mode == 0) {
                    sl.outS[(long)i * KAUG + j] = f2bf(val * acc2[m][n][r]);
                } else if (sl.mode == 1) {
                    sl.outS[(long)i * KAUG + j] = f2bf(val * sl.rs[i]);
                } else {
                    sl.outS[(long)i * DD + j] = f2bf(val);
                }
            }
}

// ---------------------------------------------------------------------------
// Context GEMM (BK=64 core), fused epilogue:
// cm = bf16((P@VDT^T * inv[i] + hB@A2tV) * mvo). mvo read as bf16.
// ---------------------------------------------------------------------------
__global__ __launch_bounds__(512)
void ctx_kernel(const short* __restrict__ P, const short* __restrict__ VDT,
                const short* __restrict__ mvo, const float* __restrict__ hB,
                const float* __restrict__ A2tV, const float* __restrict__ rowsum,
                short* __restrict__ cm)
{
    int bx = blockIdx.x, by = blockIdx.y, bz = blockIdx.z;
    xcd_swz(bx, by, bz);
    const int b = bz;
    const int bi = by * 128, bj = bx * 128;
    __shared__ __align__(16) short smem[32768];
    f32x4 acc[4][2];
    gemm_core128p8_bk64(P + (long)b * TT * TT, VDT + (long)b * DD * TT, TT, TT, TT, bi, bj, smem, acc);

    const int lane = threadIdx.x & 63, wv = threadIdx.x >> 6;
    const int wr = (wv >> 2) * 64, wc = (wv & 3) * 32;
    const int col0 = lane & 15, row0 = (lane >> 4) * 4;
    const float* a2 = A2tV + (long)b * RS * DD;

#pragma unroll
    for (int m = 0; m < 4; ++m)
#pragma unroll
        for (int r = 0; r < 4; ++r) {
            long gi = (long)b * TT + bi + wr + m*16 + row0 + r;
            float iv = 1.f / (sqrtf(rowsum[gi]) + 1e-8f);
#pragma unroll
            for (int n = 0; n < 2; ++n) acc[m][n][r] *= iv;
        }

#pragma unroll
    for (int r16 = 0; r16 < RS; ++r16) {
        float a2v[2];
#pragma unroll
        for (int n = 0; n < 2; ++n)
            a2v[n] = a2[(long)r16 * DD + bj + wc + n*16 + col0];
#pragma unroll
        for (int m = 0; m < 4; ++m)
#pragma unroll
            for (int r = 0; r < 4; ++r) {
                long gi = (long)b * TT + bi + wr + m*16 + row0 + r;
                float hb = hB[gi * RS + r16];
#pragma unroll
                for (int n = 0; n < 2; ++n)
                    acc[m][n][r] = fmaf(hb, a2v[n], acc[m][n][r]);
            }
    }
#pragma unroll
    for (int m = 0; m < 4; ++m)
#pragma unroll
        for (int n = 0; n < 2; ++n)
#pragma unroll
            for (int r = 0; r < 4; ++r) {
                long gi = (long)b * TT + bi + wr + m*16 + row0 + r;
                int j = bj + wc + n*16 + col0;
                cm[gi * DD + j] = f2bf(acc[m][n][r] * bf2f(mvo[gi * DD + j]));
            }
}

// ---------------------------------------------------------------------------
// Weight prep
// ---------------------------------------------------------------------------
struct ConcatArgs { const float* p[17]; int col0[17]; int wid[17]; };

__global__ __launch_bounds__(256)
void concat_w1_kernel(ConcatArgs a, short* __restrict__ WcatT,
                      float* __restrict__ zp, int zn)
{
    const int q = blockIdx.x * 256 + threadIdx.x;
    if (q < zn) zp[q] = 0.f;
    const int n = blockIdx.x;
    int s = -1, c = 0;
    for (int i = 0; i < 17; ++i)
        if (n >= a.col0[i] && n < a.col0[i] + a.wid[i]) { s = i; c = n - a.col0[i]; }
    for (int k = threadIdx.x; k < DD; k += 256)
        WcatT[(long)n * DD + k] = (s < 0) ? (short)0 : f2bf(a.p[s][(long)k * a.wid[s] + c]);
}

struct Ptrs8 { const float* p[8]; };

__global__ __launch_bounds__(256)
void concat_w2_kernel(Ptrs8 a, short* __restrict__ W2catT)
{
    const int s = blockIdx.y, n0 = blockIdx.x * 64;
    const int tx = threadIdx.x & 63, ty = threadIdx.x >> 6;
    __shared__ float t[64][65];
    const float* W2 = a.p[s];
    for (int kk = ty; kk < 64; kk += 4) t[kk][tx] = W2[(long)kk * DD + n0 + tx];
    __syncthreads();
    for (int n = ty; n < 64; n += 4)
        W2catT[((long)s * DD + n0 + n) * 64 + tx] = f2bf(t[tx][n]);
}

__global__ __launch_bounds__(256)
void f2bf_vec_kernel(const float* __restrict__ in, short* __restrict__ o, long n4)
{
    long i = (long)blockIdx.x * 256 + threadIdx.x;
    if (i < n4) {
        float4 v = ((const float4*)in)[i];
        short4 r; r.x = f2bf(v.x); r.y = f2bf(v.y); r.z = f2bf(v.z); r.w = f2bf(v.w);
        ((short4*)o)[i] = r;
    }
}

// zB[i][:] = qg[i][:1024] @ C1[b] (fp32 C1) -> aug cols 1024..1039
__global__ __launch_bounds__(256)
void zb_kernel(short* __restrict__ aug0, const float* __restrict__ C10)
{
    const int gi = blockIdx.x, path = blockIdx.y, b = gi >> 11, tid = threadIdx.x;
    short* aug = aug0 + (size_t)path * MT * KAUG;
    const float* c1 = C10 + (size_t)path * BB * DD * RS + (long)b * DD * RS;
    const short* qrow = aug + (long)gi * KAUG;
    float acc[RS];
#pragma unroll
    for (int r = 0; r < RS; ++r) acc[r] = 0.f;
#pragma unroll
    for (int c = 0; c < 4; ++c) {
        int d = tid + 256 * c;
        float q = bf2f(qrow[d]);
        const float* cr = c1 + (long)d * RS;
#pragma unroll
        for (int r = 0; r < RS; ++r) acc[r] = fmaf(q, cr[r], acc[r]);
    }
#pragma unroll
    for (int r = 0; r < RS; ++r)
#pragma unroll
        for (int off = 32; off; off >>= 1) acc[r] += __shfl_down(acc[r], off, 64);
    __shared__ float red[4][RS];
    if ((tid & 63) == 0)
#pragma unroll
        for (int r = 0; r < RS; ++r) red[tid >> 6][r] = acc[r];
    __syncthreads();
    if (tid < RS)
        aug[(long)gi * KAUG + 1024 + tid] =
            f2bf(red[0][tid] + red[1][tid] + red[2][tid] + red[3][tid]);
}

// ---------------------------------------------------------------------------
// vdT[b][d][t] = bf16(vb[b][t][d] * d2[b*TT+t])   (vb bf16)
// ---------------------------------------------------------------------------
__global__ __launch_bounds__(256)
void vdt_kernel(const short* __restrict__ v, const float* __restrict__ d2,
                short* __restrict__ o)
{
    const int t0 = blockIdx.x * 32, d0 = blockIdx.y * 32, b = blockIdx.z;
    const int tx = threadIdx.x & 31, ty = threadIdx.x >> 5;
    __shared__ float tile[32][33];
    for (int s = 0; s < 32; s += 8) {
        int t = t0 + ty + s;
        tile[ty + s][tx] = bf2f(v[((long)b * TT + t) * DD + d0 + tx]) * d2[(long)b * TT + t];
    }
    __syncthreads();
    for (int s = 0; s < 32; s += 8) {
        int d = d0 + ty + s;
        o[((long)b * DD + d) * TT + t0 + tx] = f2bf(tile[tx][ty + s]);
    }
}

// ---------------------------------------------------------------------------
extern "C" void kernel_launch(void* const* d_in, const int* in_sizes, int n_in,
                              void* d_out, int out_size, void* d_ws, size_t ws_size,
                              hipStream_t stream)
{
    (void)in_sizes; (void)n_in; (void)out_size; (void)ws_size;
    const float* x = (const float*)d_in[0];
    const float* W[27];
    for (int i = 1; i < 27; ++i) W[i] = (const float*)d_in[i];
    float* out = (float*)d_out;

    char* ws = (char*)d_ws;
    size_t off = 0;
    auto alloc = [&](size_t bytes) -> void* {
        void* p = ws + off; off += (bytes + 255) & ~(size_t)255; return p;
    };
    short* xb     = (short*)alloc((size_t)MT * DD * 2);          // -> VDT
    short* WcatT  = (short*)alloc((size_t)GLD * DD * 2);
    short* W2catT = (short*)alloc((size_t)8 * DD * 64 * 2);
    short* Gb512  = (short*)alloc((size_t)MT * 512 * 2);
    short* Wob    = (short*)alloc((size_t)DD * DD * 2);
    short* S1b    = (short*)alloc((size_t)MT * DD * 2);          // mvo bf16
    short* VB     = (short*)alloc((size_t)MT * DD * 2);          // v bf16
    short* QGaug  = (short*)alloc((size_t)MT * KAUG * 2);        // | contiguous
    short* QSGaug = (short*)alloc((size_t)MT * KAUG * 2);        // |
    short* KBaug  = (short*)alloc((size_t)MT * KAUG * 2);
    short* KSBaug = (short*)alloc((size_t)MT * KAUG * 2);
    short* CM     = (short*)alloc((size_t)MT * DD * 2);
    short* P      = (short*)alloc((size_t)BB * TT * TT * 2);
    float* d1   = (float*)alloc((size_t)MT * 4);
    float* d1s  = (float*)alloc((size_t)MT * 4);
    float* d2   = (float*)alloc((size_t)MT * 4);
    float* B1T  = (float*)alloc((size_t)RS * MT * 4);            // | contiguous
    float* B1sT = (float*)alloc((size_t)RS * MT * 4);            // | (e_kernel
    float* A2T  = (float*)alloc((size_t)RS * MT * 4);            // |  indexes)
    short* B2T  = (short*)alloc((size_t)RS * MT * 2);
    float* C1   = (float*)alloc((size_t)BB * DD * RS * 4);       // | contiguous
    float* C1s  = (float*)alloc((size_t)BB * DD * RS * 4);       // | (zb paths)
    float* A2tV = (float*)alloc((size_t)BB * RS * DD * 4);
    float* rowsum = (float*)alloc((size_t)MT * 4);               // | zero block
    float* E    = (float*)alloc((size_t)3 * BB * 64 * RS * 4);   // |
    float* hB   = (float*)alloc((size_t)MT * RS * 4);

    short* VDT = xb;        // xb dead after stage-1
    short* cm  = CM;

    const long n4 = (long)MT * DD / 4;
    const int ZN = MT + 3 * BB * 64 * RS;   // rowsum + E floats (contiguous)

    // --- input/weight conversion (+ zero accumulators) ---
    f2bf_vec_kernel<<<n4 / 256, 256, 0, stream>>>(x, xb, n4);
    ConcatArgs ca;
    {
        const int w1idx[8] = {1, 3, 5, 7, 9, 11, 13, 15};
        for (int s = 0; s < 8; ++s) { ca.p[s] = W[w1idx[s]]; ca.col0[s] = s * 64; ca.wid[s] = 64; }
        const int didx[9] = {18, 19, 20, 21, 22, 23, 24, 25, 26};
        const int dcol[9] = {512, 513, 529, 545, 546, 562, 578, 579, 595};
        const int dwid[9] = {1, 16, 16, 1, 16, 16, 1, 16, 16};
        for (int s = 0; s < 9; ++s) { ca.p[8 + s] = W[didx[s]]; ca.col0[8 + s] = dcol[s]; ca.wid[8 + s] = dwid[s]; }
    }
    concat_w1_kernel<<<GLD, 256, 0, stream>>>(ca, WcatT, rowsum, ZN);
    Ptrs8 p8;
    {
        const int w2idx[8] = {2, 4, 6, 8, 10, 12, 14, 16};
        for (int s = 0; s < 8; ++s) p8.p[s] = W[w2idx[s]];
    }
    concat_w2_kernel<<<dim3(DD / 64, 8), 256, 0, stream>>>(p8, W2catT);
    f2bf_vec_kernel<<<((long)DD * DD / 4) / 256, 256, 0, stream>>>(W[17], Wob, (long)DD * DD / 4);

    // --- stage-1 (SoA scatter epilogue; G never materialized) ---
    gemm_s1<<<dim3(GLD / 128, MT / 128, 1), 512, 0, stream>>>(
        xb, WcatT, Gb512, d1, d1s, d2, B1T, B1sT, A2T, B2T,
        QGaug, QSGaug, KBaug, KSBaug);

    // --- factored skinny reductions: E then C1/C1s/A2tV ---
    e_kernel<<<dim3(16, BB, 3), 256, 0, stream>>>(Gb512, B1T, E);
    c1w_kernel<<<dim3(DD / 64, 3, BB), 256, 0, stream>>>(W2catT, E, C1, A2tV);

    // --- stage-2: one launch, 6 slices ---
    S2A a;
    a.sl[0] = {0, 0, 1, QGaug,  nullptr};   // q*mg
    a.sl[1] = {0, 3, 4, QSGaug, nullptr};   // qs*mgs
    a.sl[2] = {1, 2, 0, KBaug,  d1};        // k*d1 -> aug
    a.sl[3] = {1, 5, 0, KSBaug, d1s};       // ks*d1s -> aug
    a.sl[4] = {3, 6, 0, VB,     nullptr};   // v bf16
    a.sl[5] = {3, 7, 0, S1b,    nullptr};   // mvo bf16
    stage2_kernel<<<dim3(DD / 128, MT / 128, 6), 512, 0, stream>>>(Gb512, W2catT, a);

    // --- vdT from bf16 v ---
    vdt_kernel<<<dim3(TT / 32, DD / 32, BB), 256, 0, stream>>>(VB, d2, VDT);

    // --- zB into aug cols (both paths) ---
    zb_kernel<<<dim3(MT, 2), 256, 0, stream>>>(QGaug, C1);

    // --- fused hm/hs GEMMs + HyperGLU -> P, rowsum (4-wave BK=64 core) ---
    hmhs_kernel<<<dim3(TT / 128, TT / 128, BB), 256, 0, stream>>>(
        QGaug, QSGaug, KBaug, KSBaug, P, rowsum);

    // --- finish: hB (inv folded) ---
    finish_kernel<<<dim3(TT, BB), 256, 0, stream>>>(P, B2T, rowsum, hB);

    // --- context + inv + rank16 + mvo -> cm (BK=64 core) ---
    ctx_kernel<<<dim3(DD / 128, TT / 128, BB), 512, 0, stream>>>(
        P, VDT, S1b, hB, A2tV, rowsum, cm);

    // --- out = cm @ Wo^T (BK=64 core) ---
    gemm_nt<0><<<dim3(DD / 128, MT / 128, 1), 512, 0, stream>>>(
        cm, Wob, out, DD, DD, DD, DD, 0, 0, 0);
}

// Round 19
// 249.951 us; speedup vs baseline: 1.4094x; 1.0002x over previous
//
#include <hip/hip_runtime.h>
#include <math.h>

#define BB 2
#define TT 2048
#define DD 1024
#define RS 16
#define MT (BB*TT)      // 4096 flattened rows
#define GLD 640         // stage-1 concat output width (611 used, padded)
#define KAUG 1088       // 1024 + 16 (zB/A1) + 48 zero pad; multiple of 64

typedef __attribute__((ext_vector_type(8))) short s16x8;
typedef __attribute__((ext_vector_type(4))) float f32x4;

__device__ __forceinline__ short f2bf(float f) {
    union { float f; unsigned u; } v; v.f = f;
    unsigned r = (v.u + 0x7fffu + ((v.u >> 16) & 1u)) >> 16;
    return (short)r;
}
__device__ __forceinline__ float bf2f(short s) {
    union { unsigned u; float f; } v; v.u = ((unsigned)(unsigned short)s) << 16;
    return v.f;
}

__device__ __forceinline__ void gload16(const void* g, void* l) {
    __builtin_amdgcn_global_load_lds((const __attribute__((address_space(1))) void*)g,
                                     (__attribute__((address_space(3))) void*)l, 16, 0, 0);
}

// XCD-aware block swizzle (all grids are multiples of 8 -> bijective).
__device__ __forceinline__ void xcd_swz(int& bx, int& by, int& bz)
{
    const int gx = gridDim.x, gy = gridDim.y;
    const int n = gx * gy * (int)gridDim.z;
    int flat = (bz * gy + by) * gx + bx;
    const int cpx = n >> 3;
    flat = (flat & 7) * cpx + (flat >> 3);
    bx = flat % gx; by = (flat / gx) % gy; bz = flat / (gx * gy);
}

// ---------------------------------------------------------------------------
// 8-wave (512-thr) BK=64 depth-2 core, 2M x 4N layout, acc[4][2].
// r17/r18-proven: grid-limited kernels (ctx/Wo/s1 at 1-2 blocks/CU) have
// free LDS, so 64KB double-buffered tiles halve the barrier count with no
// occupancy loss. For K=64 (stage2) nt=1: single-tile path, one stage +
// vmcnt(0) + 2 barriers + 32 MFMA (half the old BK=32 barrier count,
// bit-identical accumulation order).
// Swizzle: 8 granules/row; phys = glog ^ (row&7); inverse on global source;
// 2-way read conflict = free (m136). 4 loads/lane/tile -> steady vmcnt(4).
// Two k-sub-steps cap fragment liveness; buffer-release barrier after LAST
// read. K must be a multiple of 64.
// ---------------------------------------------------------------------------
__device__ __forceinline__ void gemm_core128p8_bk64(const short* __restrict__ A,
                                                    const short* __restrict__ Bt,
                                                    int K, int lda, int ldb,
                                                    int bi, int bj, short* smem,
                                                    f32x4 (&acc)[4][2])
{
    const int tid = threadIdx.x;
    const int wv = tid >> 6, lane = tid & 63;
    const int wr = (wv >> 2) * 64, wc = (wv & 3) * 32;

#pragma unroll
    for (int m = 0; m < 4; ++m)
#pragma unroll
        for (int n = 0; n < 2; ++n) acc[m][n] = (f32x4){0.f, 0.f, 0.f, 0.f};

    const int rloc  = lane >> 3;          // 0..7 row within the wave's 8-row group
    const int gphys = lane & 7;           // physical granule this lane writes
    const int frow  = lane & 15;
    const int gsub  = lane >> 4;          // 0..3 logical sub-granule (ks=0)

    const int nt = K >> 6;                // 64-wide K tiles

    // stage tile t into buffer q: 2 A-loads + 2 B-loads per lane
    auto stage = [&](int t, int q) {
        short* As = smem + q * 16384;     // 32KB buffer: A 8192 sh + B 8192 sh
        short* Bs = As + 8192;
        const int k0 = t << 6;
#pragma unroll
        for (int p = 0; p < 2; ++p) {
            const int row = p*64 + wv*8 + rloc;
            const int src = ((gphys ^ (row & 7)) * 8);   // inverse swizzle
            gload16(A  + (long)(bi + row) * lda + k0 + src, As + (p*64 + wv*8) * 64);
            gload16(Bt + (long)(bj + row) * ldb + k0 + src, Bs + (p*64 + wv*8) * 64);
        }
    };

    stage(0, 0);
    if (nt > 1) stage(1, 1);

    int q = 0;
    for (int t = 0; t < nt; ++t) {
        if (t + 1 < nt) asm volatile("s_waitcnt vmcnt(4)" ::: "memory");
        else            asm volatile("s_waitcnt vmcnt(0)" ::: "memory");
        __builtin_amdgcn_s_barrier();          // tile-t data visible

        const short* As = smem + q * 16384;
        const short* Bs = As + 8192;

        // ---- k-sub-step 0 (cols 0..31) ----
        {
            s16x8 af[4], bfr[2];
#pragma unroll
            for (int m = 0; m < 4; ++m) {
                const int row = wr + m*16 + frow;
                af[m] = *(const s16x8*)&As[row*64 + ((gsub ^ (row & 7)) * 8)];
            }
#pragma unroll
            for (int n = 0; n < 2; ++n) {
                const int row = wc + n*16 + frow;
                bfr[n] = *(const s16x8*)&Bs[row*64 + ((gsub ^ (row & 7)) * 8)];
            }
            asm volatile("s_waitcnt lgkmcnt(0)" ::: "memory");
            __builtin_amdgcn_sched_barrier(0);
#pragma unroll
            for (int m = 0; m < 4; ++m)
#pragma unroll
                for (int n = 0; n < 2; ++n)
                    acc[m][n] = __builtin_amdgcn_mfma_f32_16x16x32_bf16(af[m], bfr[n], acc[m][n], 0, 0, 0);
        }
        // ---- k-sub-step 1 (cols 32..63) ----
        {
            s16x8 af[4], bfr[2];
#pragma unroll
            for (int m = 0; m < 4; ++m) {
                const int row = wr + m*16 + frow;
                af[m] = *(const s16x8*)&As[row*64 + (((gsub + 4) ^ (row & 7)) * 8)];
            }
#pragma unroll
            for (int n = 0; n < 2; ++n) {
                const int row = wc + n*16 + frow;
                bfr[n] = *(const s16x8*)&Bs[row*64 + (((gsub + 4) ^ (row & 7)) * 8)];
            }
            asm volatile("s_waitcnt lgkmcnt(0)" ::: "memory");
            __builtin_amdgcn_sched_barrier(0);
            __builtin_amdgcn_s_barrier();      // all waves done READING buf q

            if (t + 2 < nt) stage(t + 2, q);   // overwrite safe; overlaps MFMA

#pragma unroll
            for (int m = 0; m < 4; ++m)
#pragma unroll
                for (int n = 0; n < 2; ++n)
                    acc[m][n] = __builtin_amdgcn_mfma_f32_16x16x32_bf16(af[m], bfr[n], acc[m][n], 0, 0, 0);
        }
        q ^= 1;
    }
}

// ---------------------------------------------------------------------------
// 4-wave (256-thr) BK=64 depth-2 core, 2x2 wave layout, acc[4][4].
// r17-proven for hmhs (51.7us, MfmaUtil 29%). Used by hmhs ONLY
// (r13: 8-wave hmhs thrashed L2; r15: no rank-16 atomics in epilogue).
// ---------------------------------------------------------------------------
__device__ __forceinline__ void gemm_core128_bk64(const short* __restrict__ A,
                                                  const short* __restrict__ Bt,
                                                  int K, int lda, int ldb,
                                                  int bi, int bj, short* smem,
                                                  f32x4 (&acc)[4][4])
{
    const int tid = threadIdx.x;
    const int wv = tid >> 6, lane = tid & 63;
    const int wr = (wv >> 1) * 64, wc = (wv & 1) * 64;

#pragma unroll
    for (int m = 0; m < 4; ++m)
#pragma unroll
        for (int n = 0; n < 4; ++n) acc[m][n] = (f32x4){0.f, 0.f, 0.f, 0.f};

    const int rloc  = lane >> 3;          // 0..7 row within an 8-row group
    const int gphys = lane & 7;           // physical granule this lane writes
    const int frow  = lane & 15;
    const int gsub  = lane >> 4;          // 0..3 logical sub-granule (ks=0)

    const int nt = K >> 6;                // 64-wide K tiles

    auto stage = [&](int t, int q) {
        short* As = smem + q * 16384;     // 32KB buffer: A 8192 sh + B 8192 sh
        short* Bs = As + 8192;
        const int k0 = t << 6;
#pragma unroll
        for (int p = 0; p < 4; ++p) {
            const int row = p*32 + wv*8 + rloc;
            const int src = ((gphys ^ (row & 7)) * 8);   // inverse swizzle
            gload16(A  + (long)(bi + row) * lda + k0 + src, As + (p*32 + wv*8) * 64);
            gload16(Bt + (long)(bj + row) * ldb + k0 + src, Bs + (p*32 + wv*8) * 64);
        }
    };

    stage(0, 0);
    if (nt > 1) stage(1, 1);

    int q = 0;
    for (int t = 0; t < nt; ++t) {
        if (t + 1 < nt) asm volatile("s_waitcnt vmcnt(8)" ::: "memory");
        else            asm volatile("s_waitcnt vmcnt(0)" ::: "memory");
        __builtin_amdgcn_s_barrier();          // tile-t data visible

        const short* As = smem + q * 16384;
        const short* Bs = As + 8192;

        // ---- k-sub-step 0 (cols 0..31 of the tile) ----
        {
            s16x8 af[4], bfr[4];
#pragma unroll
            for (int m = 0; m < 4; ++m) {
                const int row = wr + m*16 + frow;
                af[m] = *(const s16x8*)&As[row*64 + ((gsub ^ (row & 7)) * 8)];
            }
#pragma unroll
            for (int n = 0; n < 4; ++n) {
                const int row = wc + n*16 + frow;
                bfr[n] = *(const s16x8*)&Bs[row*64 + ((gsub ^ (row & 7)) * 8)];
            }
            asm volatile("s_waitcnt lgkmcnt(0)" ::: "memory");
            __builtin_amdgcn_sched_barrier(0);
#pragma unroll
            for (int m = 0; m < 4; ++m)
#pragma unroll
                for (int n = 0; n < 4; ++n)
                    acc[m][n] = __builtin_amdgcn_mfma_f32_16x16x32_bf16(af[m], bfr[n], acc[m][n], 0, 0, 0);
        }
        // ---- k-sub-step 1 (cols 32..63) ----
        {
            s16x8 af[4], bfr[4];
#pragma unroll
            for (int m = 0; m < 4; ++m) {
                const int row = wr + m*16 + frow;
                af[m] = *(const s16x8*)&As[row*64 + (((gsub + 4) ^ (row & 7)) * 8)];
            }
#pragma unroll
            for (int n = 0; n < 4; ++n) {
                const int row = wc + n*16 + frow;
                bfr[n] = *(const s16x8*)&Bs[row*64 + (((gsub + 4) ^ (row & 7)) * 8)];
            }
            asm volatile("s_waitcnt lgkmcnt(0)" ::: "memory");
            __builtin_amdgcn_sched_barrier(0);
            __builtin_amdgcn_s_barrier();      // all waves done READING buf q

            if (t + 2 < nt) stage(t + 2, q);   // overwrite safe; overlaps MFMA

#pragma unroll
            for (int m = 0; m < 4; ++m)
#pragma unroll
                for (int n = 0; n < 4; ++n)
                    acc[m][n] = __builtin_amdgcn_mfma_f32_16x16x32_bf16(af[m], bfr[n], acc[m][n], 0, 0, 0);
        }
        q ^= 1;
    }
}

// Generic batched NT GEMM (BK=64 core); STORE 0 = fp32 out, 1 = bf16 out.
template<int STORE>
__global__ __launch_bounds__(512)
void gemm_nt(const short* __restrict__ A, const short* __restrict__ Bt,
             void* __restrict__ Cv, int K, int lda, int ldb, int ldc,
             long sA, long sB, long sC)
{
    int bx = blockIdx.x, by = blockIdx.y, bz = blockIdx.z;
    xcd_swz(bx, by, bz);
    const short* Ab = A  + (long)bz * sA;
    const short* Bb = Bt + (long)bz * sB;
    const int bi = by * 128, bj = bx * 128;
    __shared__ __align__(16) short smem[32768];
    f32x4 acc[4][2];
    gemm_core128p8_bk64(Ab, Bb, K, lda, ldb, bi, bj, smem, acc);

    const int lane = threadIdx.x & 63, wv = threadIdx.x >> 6;
    const int wr = (wv >> 2) * 64, wc = (wv & 3) * 32;
    const int col0 = lane & 15, row0 = (lane >> 4) * 4;
#pragma unroll
    for (int m = 0; m < 4; ++m)
#pragma unroll
        for (int n = 0; n < 2; ++n)
#pragma unroll
            for (int r = 0; r < 4; ++r) {
                int i = bi + wr + m*16 + row0 + r;
                int j = bj + wc + n*16 + col0;
                if (STORE == 0)
                    ((float*)Cv + (long)bz * sC)[(long)i * ldc + j] = acc[m][n][r];
                else
                    ((short*)Cv + (long)bz * sC)[(long)i * ldc + j] = f2bf(acc[m][n][r]);
            }
}

// ---------------------------------------------------------------------------
// Stage-1: xb @ WcatT^T (BK=64 core). Epilogue: cols <512 -> Gb512 bf16;
// cols 512..610 scattered directly to SoA generator arrays (G never stored).
// Also zeroes aug pad cols 1040..1087 (at j==512, once per row).
// ---------------------------------------------------------------------------
__global__ __launch_bounds__(512)
void gemm_s1(const short* __restrict__ xb, const short* __restrict__ WcatT,
             short* __restrict__ Gb512,
             float* __restrict__ d1, float* __restrict__ d1s, float* __restrict__ d2,
             float* __restrict__ B1T, float* __restrict__ B1sT, float* __restrict__ A2T,
             short* __restrict__ B2T,
             short* __restrict__ QGaug, short* __restrict__ QSGaug,
             short* __restrict__ KBaug, short* __restrict__ KSBaug)
{
    int bx = blockIdx.x, by = blockIdx.y, bz = blockIdx.z;
    xcd_swz(bx, by, bz);
    const int bi = by * 128, bj = bx * 128;
    __shared__ __align__(16) short smem[32768];
    f32x4 acc[4][2];
    gemm_core128p8_bk64(xb, WcatT, DD, DD, DD, bi, bj, smem, acc);

    const int lane = threadIdx.x & 63, wv = threadIdx.x >> 6;
    const int wr = (wv >> 2) * 64, wc = (wv & 3) * 32;
    const int col0 = lane & 15, row0 = (lane >> 4) * 4;
#pragma unroll
    for (int m = 0; m < 4; ++m)
#pragma unroll
        for (int n = 0; n < 2; ++n)
#pragma unroll
            for (int r = 0; r < 4; ++r) {
                int i = bi + wr + m*16 + row0 + r;
                int j = bj + wc + n*16 + col0;
                float val = acc[m][n][r];
                if (j < 512) {
                    Gb512[(long)i * 512 + j] = f2bf(val);
                } else if (j == 512) {
                    d1[i] = val;
                    for (int q = 0; q < KAUG - 1040; ++q) {
                        QGaug [(long)i * KAUG + 1040 + q] = 0;
                        QSGaug[(long)i * KAUG + 1040 + q] = 0;
                        KBaug [(long)i * KAUG + 1040 + q] = 0;
                        KSBaug[(long)i * KAUG + 1040 + q] = 0;
                    }
                } else if (j < 529) {
                    KBaug[(long)i * KAUG + 1024 + (j - 513)] = f2bf(val);
                } else if (j < 545) {
                    B1T[(long)(j - 529) * MT + i] = val;
                } else if (j == 545) {
                    d1s[i] = val;
                } else if (j < 562) {
                    KSBaug[(long)i * KAUG + 1024 + (j - 546)] = f2bf(val);
                } else if (j < 578) {
                    B1sT[(long)(j - 562) * MT + i] = val;
                } else if (j == 578) {
                    d2[i] = val;
                } else if (j < 595) {
                    A2T[(long)(j - 579) * MT + i] = val;
                } else if (j < 611) {
                    B2T[(long)(j - 595) * MT + i] = f2bf(val);
                }
            }
}

// ---------------------------------------------------------------------------
// E[kind][b][c][r] = sum_t Gb512[b*TT+t][col0(kind)+c] * BT_kind[r][b*TT+t]
// ---------------------------------------------------------------------------
__global__ __launch_bounds__(256)
void e_kernel(const short* __restrict__ Gb512, const float* __restrict__ BT0,
              float* __restrict__ E)
{
    const int tc = blockIdx.x, b = blockIdx.y, kind = blockIdx.z;
    const int col0 = (kind == 0) ? 128 : (kind == 1) ? 320 : 384;
    const float* BT = BT0 + (size_t)kind * RS * MT;
    const int c = threadIdx.x & 63, rg = threadIdx.x >> 6;
    float acc[4] = {0.f, 0.f, 0.f, 0.f};
    const int t0 = tc * (TT / 16);
#pragma unroll 2
    for (int tt = 0; tt < TT / 16; ++tt) {
        const long gi = (long)b * TT + t0 + tt;
        float g = bf2f(Gb512[gi * 512 + col0 + c]);
#pragma unroll
        for (int q = 0; q < 4; ++q)
            acc[q] = fmaf(g, BT[(long)(rg * 4 + q) * MT + gi], acc[q]);
    }
#pragma unroll
    for (int q = 0; q < 4; ++q)
        atomicAdd(&E[(((long)kind * BB + b) * 64 + c) * RS + rg * 4 + q], acc[q]);
}

// ---------------------------------------------------------------------------
// c1w: C1[kind][b][d][r] = sum_c W2T[s(kind)][d][c] * E[kind][b][c][r]
// kind 2 writes A2tV[b][r][d] layout instead.
// ---------------------------------------------------------------------------
__global__ __launch_bounds__(256)
void c1w_kernel(const short* __restrict__ W2, const float* __restrict__ E,
                float* __restrict__ C1, float* __restrict__ A2tV)
{
    const int d0 = blockIdx.x * 64, kind = blockIdx.y, b = blockIdx.z;
    const int s = (kind == 0) ? 2 : (kind == 1) ? 5 : 6;
    __shared__ float El[64][RS];
    {
        const float* Eb = E + ((long)kind * BB + b) * 64 * RS;
        int q = threadIdx.x;
#pragma unroll
        for (int k = 0; k < 4; ++k) ((float*)El)[q + 256 * k] = Eb[q + 256 * k];
    }
    __syncthreads();
    const int dl = threadIdx.x & 63, rg = threadIdx.x >> 6;
    const int d = d0 + dl;
    const short* wrow = W2 + ((long)s * DD + d) * 64;
    float acc[4] = {0.f, 0.f, 0.f, 0.f};
#pragma unroll
    for (int c8 = 0; c8 < 8; ++c8) {
        s16x8 wv = *(const s16x8*)&wrow[c8 * 8];
#pragma unroll
        for (int u = 0; u < 8; ++u) {
            float w = bf2f(wv[u]);
#pragma unroll
            for (int q = 0; q < 4; ++q)
                acc[q] = fmaf(w, El[c8 * 8 + u][rg * 4 + q], acc[q]);
        }
    }
    if (kind < 2) {
        float* dst = C1 + (size_t)kind * BB * DD * RS;
#pragma unroll
        for (int q = 0; q < 4; ++q)
            dst[((long)b * DD + d) * RS + rg * 4 + q] = acc[q];
    } else {
#pragma unroll
        for (int q = 0; q < 4; ++q)
            A2tV[((long)b * RS + rg * 4 + q) * DD + d] = acc[q];
    }
}

// ---------------------------------------------------------------------------
// hmhs_fused: two sequential 4-wave BK=64 depth-2 core passes (gate, scale),
// 64 KB LDS, 256 threads (r17-proven: 51.7us). Epilogue:
// P = fast_softplus(hs) * relu(hm) (bf16, norm deferred), rowsum += hm^2.
// ---------------------------------------------------------------------------
__global__ __launch_bounds__(256)
void hmhs_kernel(const short* __restrict__ QGaug, const short* __restrict__ QSGaug,
                 const short* __restrict__ KBaug, const short* __restrict__ KSBaug,
                 short* __restrict__ P, float* __restrict__ rowsum)
{
    int bx = blockIdx.x, by = blockIdx.y, bz = blockIdx.z;
    xcd_swz(bx, by, bz);
    const int b = bz;
    const int bi = by * 128, bj = bx * 128;
    __shared__ __align__(16) short smem[32768];   // 64 KB: 2 x (16KB A + 16KB B)
    f32x4 acc[4][4], acc2[4][4];
    gemm_core128_bk64(QGaug  + (long)b * TT * KAUG, KBaug  + (long)b * TT * KAUG,
                      KAUG, KAUG, KAUG, bi, bj, smem, acc);
    gemm_core128_bk64(QSGaug + (long)b * TT * KAUG, KSBaug + (long)b * TT * KAUG,
                      KAUG, KAUG, KAUG, bi, bj, smem, acc2);

    const int lane = threadIdx.x & 63, wv = threadIdx.x >> 6;
    const int wr = (wv >> 1) * 64, wc = (wv & 1) * 64;
    const int col0 = lane & 15, row0 = (lane >> 4) * 4;
    short* Pb = P + (long)b * TT * TT;

    float ss[4][4];
#pragma unroll
    for (int m = 0; m < 4; ++m)
#pragma unroll
        for (int r = 0; r < 4; ++r) ss[m][r] = 0.f;

#pragma unroll
    for (int m = 0; m < 4; ++m)
#pragma unroll
        for (int n = 0; n < 4; ++n)
#pragma unroll
            for (int r = 0; r < 4; ++r) {
                int i = bi + wr + m*16 + row0 + r;
                int j = bj + wc + n*16 + col0;
                float hmv = acc[m][n][r];
                float sv  = acc2[m][n][r];
                // fast softplus: 2 HW transcendentals (error << bf16 rounding)
                float sp  = fmaxf(sv, 0.f) + __logf(1.f + __expf(-fabsf(sv)));
                Pb[(long)i * TT + j] = f2bf(sp * fmaxf(hmv, 0.f));
                ss[m][r] = fmaf(hmv, hmv, ss[m][r]);
            }

#pragma unroll
    for (int m = 0; m < 4; ++m)
#pragma unroll
        for (int r = 0; r < 4; ++r) {
            float v = ss[m][r];
            v += __shfl_xor(v, 1, 64);
            v += __shfl_xor(v, 2, 64);
            v += __shfl_xor(v, 4, 64);
            v += __shfl_xor(v, 8, 64);
            if (col0 == 0)
                atomicAdd(&rowsum[(long)b * TT + bi + wr + m*16 + row0 + r], v);
        }
}

// ---------------------------------------------------------------------------
// finish: hB[i][r] = inv[i] * sum_j P[i][j] * B2T[r][j]
// ---------------------------------------------------------------------------
__global__ __launch_bounds__(256)
void finish_kernel(const short* __restrict__ P, const short* __restrict__ B2T,
                   const float* __restrict__ rowsum, float* __restrict__ hB)
{
    const int i = blockIdx.x, b = blockIdx.y, tid = threadIdx.x;
    const long gi = (long)b * TT + i;
    const float inv = 1.f / (sqrtf(rowsum[gi]) + 1e-8f);
    const short* Pr = P + ((long)b * TT + i) * TT;
    const long tb = (long)b * TT;
    const int j0 = tid * 8;

    float hb[RS];
#pragma unroll
    for (int r = 0; r < RS; ++r) hb[r] = 0.f;

    s16x8 pv = *(const s16x8*)&Pr[j0];
    float pf[8];
#pragma unroll
    for (int q = 0; q < 8; ++q) pf[q] = bf2f(pv[q]);
#pragma unroll
    for (int r = 0; r < RS; ++r) {
        s16x8 bv = *(const s16x8*)&B2T[(long)r * MT + tb + j0];
#pragma unroll
        for (int q = 0; q < 8; ++q) hb[r] = fmaf(pf[q], bf2f(bv[q]), hb[r]);
    }
#pragma unroll
    for (int r = 0; r < RS; ++r)
#pragma unroll
        for (int off = 32; off; off >>= 1) hb[r] += __shfl_down(hb[r], off, 64);
    __shared__ float red[4][RS];
    if ((tid & 63) == 0)
#pragma unroll
        for (int r = 0; r < RS; ++r) red[tid >> 6][r] = hb[r];
    __syncthreads();
    if (tid < RS)
        hB[gi * RS + tid] = (red[0][tid] + red[1][tid] + red[2][tid] + red[3][tid]) * inv;
}

// ---------------------------------------------------------------------------
// Stage-2 multi-slice GEMM (K=64 per pass, BK=64 single-tile path:
// one stage + vmcnt(0) + 2 barriers + 32 MFMA per pass -- half the old
// BK=32 barrier count, bit-identical accumulation order).
// mode 0 (GATE):   two passes (sa,sb); out bf16(acc*acc2) at ldc KAUG.
// mode 1 (SCALED): outS bf16(acc*rs[i]) at ldc KAUG.
// mode 3 (BF16):   outS bf16 ldc DD.
// ---------------------------------------------------------------------------
struct S2S { int mode, sa, sb; short* outS; const float* rs; };
struct S2A { S2S sl[6]; };

__global__ __launch_bounds__(512)
void stage2_kernel(const short* __restrict__ Gb, const short* __restrict__ W2,
                   S2A args)
{
    int bx = blockIdx.x, by = blockIdx.y, bz = blockIdx.z;
    xcd_swz(bx, by, bz);
    const S2S sl = args.sl[bz];
    const int bi = by * 128, bj = bx * 128;
    __shared__ __align__(16) short smem[16384];   // 32KB single buffer (nt=1)
    f32x4 acc[4][2];
    gemm_core128p8_bk64(Gb + sl.sa * 64, W2 + (long)sl.sa * DD * 64, 64, 512, 64, bi, bj, smem, acc);
    f32x4 acc2[4][2];
    if (sl.mode == 0)
        gemm_core128p8_bk64(Gb + sl.sb * 64, W2 + (long)sl.sb * DD * 64, 64, 512, 64, bi, bj, smem, acc2);

    const int lane = threadIdx.x & 63, wv = threadIdx.x >> 6;
    const int wr = (wv >> 2) * 64, wc = (wv & 3) * 32;
    const int col0 = lane & 15, row0 = (lane >> 4) * 4;
#pragma unroll
    for (int m = 0; m < 4; ++m)
#pragma unroll
        for (int n = 0; n < 2; ++n)
#pragma unroll
            for (int r = 0; r < 4; ++r) {
                int i = bi + wr + m*16 + row0 + r;
                int j = bj + wc + n*16 + col0;
                float val = acc[m][n][r];
                if (sl.mode == 0) {
                    sl.outS[(long)i * KAUG + j] = f2bf(val * acc2[m][n][r]);
                } else if (sl.mode == 1) {
                    sl.outS[(long)i * KAUG + j] = f2bf(val * sl.rs[i]);
                } else {
                    sl.outS[(long)i * DD + j] = f2bf(val);
                }
            }
}

// ---------------------------------------------------------------------------
// Context GEMM (BK=64 core), fused epilogue:
// cm = bf16((P@VDT^T * inv[i] + hB@A2tV) * mvo). mvo read as bf16.
// ---------------------------------------------------------------------------
__global__ __launch_bounds__(512)
void ctx_kernel(const short* __restrict__ P, const short* __restrict__ VDT,
                const short* __restrict__ mvo, const float* __restrict__ hB,
                const float* __restrict__ A2tV, const float* __restrict__ rowsum,
                short* __restrict__ cm)
{
    int bx = blockIdx.x, by = blockIdx.y, bz = blockIdx.z;
    xcd_swz(bx, by, bz);
    const int b = bz;
    const int bi = by * 128, bj = bx * 128;
    __shared__ __align__(16) short smem[32768];
    f32x4 acc[4][2];
    gemm_core128p8_bk64(P + (long)b * TT * TT, VDT + (long)b * DD * TT, TT, TT, TT, bi, bj, smem, acc);

    const int lane = threadIdx.x & 63, wv = threadIdx.x >> 6;
    const int wr = (wv >> 2) * 64, wc = (wv & 3) * 32;
    const int col0 = lane & 15, row0 = (lane >> 4) * 4;
    const float* a2 = A2tV + (long)b * RS * DD;

#pragma unroll
    for (int m = 0; m < 4; ++m)
#pragma unroll
        for (int r = 0; r < 4; ++r) {
            long gi = (long)b * TT + bi + wr + m*16 + row0 + r;
            float iv = 1.f / (sqrtf(rowsum[gi]) + 1e-8f);
#pragma unroll
            for (int n = 0; n < 2; ++n) acc[m][n][r] *= iv;
        }

#pragma unroll
    for (int r16 = 0; r16 < RS; ++r16) {
        float a2v[2];
#pragma unroll
        for (int n = 0; n < 2; ++n)
            a2v[n] = a2[(long)r16 * DD + bj + wc + n*16 + col0];
#pragma unroll
        for (int m = 0; m < 4; ++m)
#pragma unroll
            for (int r = 0; r < 4; ++r) {
                long gi = (long)b * TT + bi + wr + m*16 + row0 + r;
                float hb = hB[gi * RS + r16];
#pragma unroll
                for (int n = 0; n < 2; ++n)
                    acc[m][n][r] = fmaf(hb, a2v[n], acc[m][n][r]);
            }
    }
#pragma unroll
    for (int m = 0; m < 4; ++m)
#pragma unroll
        for (int n = 0; n < 2; ++n)
#pragma unroll
            for (int r = 0; r < 4; ++r) {
                long gi = (long)b * TT + bi + wr + m*16 + row0 + r;
                int j = bj + wc + n*16 + col0;
                cm[gi * DD + j] = f2bf(acc[m][n][r] * bf2f(mvo[gi * DD + j]));
            }
}

// ---------------------------------------------------------------------------
// Weight prep
// ---------------------------------------------------------------------------
struct ConcatArgs { const float* p[17]; int col0[17]; int wid[17]; };

__global__ __launch_bounds__(256)
void concat_w1_kernel(ConcatArgs a, short* __restrict__ WcatT,
                      float* __restrict__ zp, int zn)
{
    const int q = blockIdx.x * 256 + threadIdx.x;
    if (q < zn) zp[q] = 0.f;
    const int n = blockIdx.x;
    int s = -1, c = 0;
    for (int i = 0; i < 17; ++i)
        if (n >= a.col0[i] && n < a.col0[i] + a.wid[i]) { s = i; c = n - a.col0[i]; }
    for (int k = threadIdx.x; k < DD; k += 256)
        WcatT[(long)n * DD + k] = (s < 0) ? (short)0 : f2bf(a.p[s][(long)k * a.wid[s] + c]);
}

struct Ptrs8 { const float* p[8]; };

__global__ __launch_bounds__(256)
void concat_w2_kernel(Ptrs8 a, short* __restrict__ W2catT)
{
    const int s = blockIdx.y, n0 = blockIdx.x * 64;
    const int tx = threadIdx.x & 63, ty = threadIdx.x >> 6;
    __shared__ float t[64][65];
    const float* W2 = a.p[s];
    for (int kk = ty; kk < 64; kk += 4) t[kk][tx] = W2[(long)kk * DD + n0 + tx];
    __syncthreads();
    for (int n = ty; n < 64; n += 4)
        W2catT[((long)s * DD + n0 + n) * 64 + tx] = f2bf(t[tx][n]);
}

__global__ __launch_bounds__(256)
void f2bf_vec_kernel(const float* __restrict__ in, short* __restrict__ o, long n4)
{
    long i = (long)blockIdx.x * 256 + threadIdx.x;
    if (i < n4) {
        float4 v = ((const float4*)in)[i];
        short4 r; r.x = f2bf(v.x); r.y = f2bf(v.y); r.z = f2bf(v.z); r.w = f2bf(v.w);
        ((short4*)o)[i] = r;
    }
}

// zB[i][:] = qg[i][:1024] @ C1[b] (fp32 C1) -> aug cols 1024..1039
__global__ __launch_bounds__(256)
void zb_kernel(short* __restrict__ aug0, const float* __restrict__ C10)
{
    const int gi = blockIdx.x, path = blockIdx.y, b = gi >> 11, tid = threadIdx.x;
    short* aug = aug0 + (size_t)path * MT * KAUG;
    const float* c1 = C10 + (size_t)path * BB * DD * RS + (long)b * DD * RS;
    const short* qrow = aug + (long)gi * KAUG;
    float acc[RS];
#pragma unroll
    for (int r = 0; r < RS; ++r) acc[r] = 0.f;
#pragma unroll
    for (int c = 0; c < 4; ++c) {
        int d = tid + 256 * c;
        float q = bf2f(qrow[d]);
        const float* cr = c1 + (long)d * RS;
#pragma unroll
        for (int r = 0; r < RS; ++r) acc[r] = fmaf(q, cr[r], acc[r]);
    }
#pragma unroll
    for (int r = 0; r < RS; ++r)
#pragma unroll
        for (int off = 32; off; off >>= 1) acc[r] += __shfl_down(acc[r], off, 64);
    __shared__ float red[4][RS];
    if ((tid & 63) == 0)
#pragma unroll
        for (int r = 0; r < RS; ++r) red[tid >> 6][r] = acc[r];
    __syncthreads();
    if (tid < RS)
        aug[(long)gi * KAUG + 1024 + tid] =
            f2bf(red[0][tid] + red[1][tid] + red[2][tid] + red[3][tid]);
}

// ---------------------------------------------------------------------------
// vdT[b][d][t] = bf16(vb[b][t][d] * d2[b*TT+t])   (vb bf16)
// ---------------------------------------------------------------------------
__global__ __launch_bounds__(256)
void vdt_kernel(const short* __restrict__ v, const float* __restrict__ d2,
                short* __restrict__ o)
{
    const int t0 = blockIdx.x * 32, d0 = blockIdx.y * 32, b = blockIdx.z;
    const int tx = threadIdx.x & 31, ty = threadIdx.x >> 5;
    __shared__ float tile[32][33];
    for (int s = 0; s < 32; s += 8) {
        int t = t0 + ty + s;
        tile[ty + s][tx] = bf2f(v[((long)b * TT + t) * DD + d0 + tx]) * d2[(long)b * TT + t];
    }
    __syncthreads();
    for (int s = 0; s < 32; s += 8) {
        int d = d0 + ty + s;
        o[((long)b * DD + d) * TT + t0 + tx] = f2bf(tile[tx][ty + s]);
    }
}

// ---------------------------------------------------------------------------
extern "C" void kernel_launch(void* const* d_in, const int* in_sizes, int n_in,
                              void* d_out, int out_size, void* d_ws, size_t ws_size,
                              hipStream_t stream)
{
    (void)in_sizes; (void)n_in; (void)out_size; (void)ws_size;
    const float* x = (const float*)d_in[0];
    const float* W[27];
    for (int i = 1; i < 27; ++i) W[i] = (const float*)d_in[i];
    float* out = (float*)d_out;

    char* ws = (char*)d_ws;
    size_t off = 0;
    auto alloc = [&](size_t bytes) -> void* {
        void* p = ws + off; off += (bytes + 255) & ~(size_t)255; return p;
    };
    short* xb     = (short*)alloc((size_t)MT * DD * 2);          // -> VDT
    short* WcatT  = (short*)alloc((size_t)GLD * DD * 2);
    short* W2catT = (short*)alloc((size_t)8 * DD * 64 * 2);
    short* Gb512  = (short*)alloc((size_t)MT * 512 * 2);
    short* Wob    = (short*)alloc((size_t)DD * DD * 2);
    short* S1b    = (short*)alloc((size_t)MT * DD * 2);          // mvo bf16
    short* VB     = (short*)alloc((size_t)MT * DD * 2);          // v bf16
    short* QGaug  = (short*)alloc((size_t)MT * KAUG * 2);        // | contiguous
    short* QSGaug = (short*)alloc((size_t)MT * KAUG * 2);        // |
    short* KBaug  = (short*)alloc((size_t)MT * KAUG * 2);
    short* KSBaug = (short*)alloc((size_t)MT * KAUG * 2);
    short* CM     = (short*)alloc((size_t)MT * DD * 2);
    short* P      = (short*)alloc((size_t)BB * TT * TT * 2);
    float* d1   = (float*)alloc((size_t)MT * 4);
    float* d1s  = (float*)alloc((size_t)MT * 4);
    float* d2   = (float*)alloc((size_t)MT * 4);
    float* B1T  = (float*)alloc((size_t)RS * MT * 4);            // | contiguous
    float* B1sT = (float*)alloc((size_t)RS * MT * 4);            // | (e_kernel
    float* A2T  = (float*)alloc((size_t)RS * MT * 4);            // |  indexes)
    short* B2T  = (short*)alloc((size_t)RS * MT * 2);
    float* C1   = (float*)alloc((size_t)BB * DD * RS * 4);       // | contiguous
    float* C1s  = (float*)alloc((size_t)BB * DD * RS * 4);       // | (zb paths)
    float* A2tV = (float*)alloc((size_t)BB * RS * DD * 4);
    float* rowsum = (float*)alloc((size_t)MT * 4);               // | zero block
    float* E    = (float*)alloc((size_t)3 * BB * 64 * RS * 4);   // |
    float* hB   = (float*)alloc((size_t)MT * RS * 4);

    short* VDT = xb;        // xb dead after stage-1
    short* cm  = CM;

    const long n4 = (long)MT * DD / 4;
    const int ZN = MT + 3 * BB * 64 * RS;   // rowsum + E floats (contiguous)

    // --- input/weight conversion (+ zero accumulators) ---
    f2bf_vec_kernel<<<n4 / 256, 256, 0, stream>>>(x, xb, n4);
    ConcatArgs ca;
    {
        const int w1idx[8] = {1, 3, 5, 7, 9, 11, 13, 15};
        for (int s = 0; s < 8; ++s) { ca.p[s] = W[w1idx[s]]; ca.col0[s] = s * 64; ca.wid[s] = 64; }
        const int didx[9] = {18, 19, 20, 21, 22, 23, 24, 25, 26};
        const int dcol[9] = {512, 513, 529, 545, 546, 562, 578, 579, 595};
        const int dwid[9] = {1, 16, 16, 1, 16, 16, 1, 16, 16};
        for (int s = 0; s < 9; ++s) { ca.p[8 + s] = W[didx[s]]; ca.col0[8 + s] = dcol[s]; ca.wid[8 + s] = dwid[s]; }
    }
    concat_w1_kernel<<<GLD, 256, 0, stream>>>(ca, WcatT, rowsum, ZN);
    Ptrs8 p8;
    {
        const int w2idx[8] = {2, 4, 6, 8, 10, 12, 14, 16};
        for (int s = 0; s < 8; ++s) p8.p[s] = W[w2idx[s]];
    }
    concat_w2_kernel<<<dim3(DD / 64, 8), 256, 0, stream>>>(p8, W2catT);
    f2bf_vec_kernel<<<((long)DD * DD / 4) / 256, 256, 0, stream>>>(W[17], Wob, (long)DD * DD / 4);

    // --- stage-1 (SoA scatter epilogue; G never materialized) ---
    gemm_s1<<<dim3(GLD / 128, MT / 128, 1), 512, 0, stream>>>(
        xb, WcatT, Gb512, d1, d1s, d2, B1T, B1sT, A2T, B2T,
        QGaug, QSGaug, KBaug, KSBaug);

    // --- factored skinny reductions: E then C1/C1s/A2tV ---
    e_kernel<<<dim3(16, BB, 3), 256, 0, stream>>>(Gb512, B1T, E);
    c1w_kernel<<<dim3(DD / 64, 3, BB), 256, 0, stream>>>(W2catT, E, C1, A2tV);

    // --- stage-2: one launch, 6 slices (BK=64 single-tile path) ---
    S2A a;
    a.sl[0] = {0, 0, 1, QGaug,  nullptr};   // q*mg
    a.sl[1] = {0, 3, 4, QSGaug, nullptr};   // qs*mgs
    a.sl[2] = {1, 2, 0, KBaug,  d1};        // k*d1 -> aug
    a.sl[3] = {1, 5, 0, KSBaug, d1s};       // ks*d1s -> aug
    a.sl[4] = {3, 6, 0, VB,     nullptr};   // v bf16
    a.sl[5] = {3, 7, 0, S1b,    nullptr};   // mvo bf16
    stage2_kernel<<<dim3(DD / 128, MT / 128, 6), 512, 0, stream>>>(Gb512, W2catT, a);

    // --- vdT from bf16 v ---
    vdt_kernel<<<dim3(TT / 32, DD / 32, BB), 256, 0, stream>>>(VB, d2, VDT);

    // --- zB into aug cols (both paths) ---
    zb_kernel<<<dim3(MT, 2), 256, 0, stream>>>(QGaug, C1);

    // --- fused hm/hs GEMMs + HyperGLU -> P, rowsum (4-wave BK=64 core) ---
    hmhs_kernel<<<dim3(TT / 128, TT / 128, BB), 256, 0, stream>>>(
        QGaug, QSGaug, KBaug, KSBaug, P, rowsum);

    // --- finish: hB (inv folded) ---
    finish_kernel<<<dim3(TT, BB), 256, 0, stream>>>(P, B2T, rowsum, hB);

    // --- context + inv + rank16 + mvo -> cm (BK=64 core) ---
    ctx_kernel<<<dim3(DD / 128, TT / 128, BB), 512, 0, stream>>>(
        P, VDT, S1b, hB, A2tV, rowsum, cm);

    // --- out = cm @ Wo^T (BK=64 core) ---
    gemm_nt<0><<<dim3(DD / 128, MT / 128, 1), 512, 0, stream>>>(
        cm, Wob, out, DD, DD, DD, DD, 0, 0, 0);
}